// Round 13
// baseline (208.295 us; speedup 1.0000x reference)
//
#include <hip/hip_runtime.h>
#include <math.h>

#define BB   4
#define LSEQ 2048
#define DV   256
#define HH   4
#define RR   128
#define EE   32768
#define ETOT (EE + LSEQ)
#define FFD  1024

typedef unsigned short u16;
typedef __attribute__((ext_vector_type(8))) short bf16x8;
typedef __attribute__((ext_vector_type(4))) float f32x4;

__device__ __forceinline__ u16 f2bf(float f) {
    union { float f; unsigned u; } x; x.f = f;
    unsigned r = x.u + 0x7fff + ((x.u >> 16) & 1);
    return (u16)(r >> 16);
}
__device__ __forceinline__ float bf2f(u16 u) {
    union { unsigned u; float f; } x; x.u = ((unsigned)u) << 16;
    return x.f;
}

__device__ __forceinline__ void gload16(const void* g, void* l) {
    __builtin_amdgcn_global_load_lds(
        (const __attribute__((address_space(1))) unsigned int*)g,
        (__attribute__((address_space(3))) unsigned int*)l, 16, 0, 0);
}

// ---------------------------------------------------------------------------
// bf16 MFMA GEMM. BM in {128,64}, BN in {128,64}, BK=64. (verified)
// ---------------------------------------------------------------------------
template<int BM, int BN, int OUTBF16, int ACT>
__global__ __launch_bounds__(256) void mfma_gemm_k(
    const u16* __restrict__ A, const u16* __restrict__ BT,
    const float* __restrict__ bias, void* __restrict__ Cv,
    int M, int N, int K, int lda, int ldb, int ldc,
    long bsA1, long bsA2, long bsB1, long bsB2, long bsC1, long bsC2,
    int subH, long pairB, long pairC, int ksl, int split, float alpha)
{
    constexpr int BK = 64;
    __shared__ u16 As[BM * BK];
    __shared__ u16 Bs[BN * BK];

    int z = blockIdx.z;
    int zb = z / subH, zh = z - zb * subH;
    int mtiles = M / BM;
    int pair = blockIdx.y / mtiles;
    int mt   = blockIdx.y - pair * mtiles;

    const u16* Ab = A  + zb * bsA1 + zh * bsA2;
    const u16* Bb = BT + zb * bsB1 + zh * bsB2 + (long)pair * pairB;
    int kstart = split ? zh * ksl : 0;
    int kcount = split ? ksl : K;
    int m0 = mt * BM, n0 = blockIdx.x * BN;

    int tid  = threadIdx.x;
    int wave = tid >> 6, lane = tid & 63;
    constexpr int WGN = (BN == 128) ? 2 : 1;
    constexpr int WGM = 4 / WGN;
    constexpr int MI  = BM / (WGM * 16);
    constexpr int NI  = BN / (WGN * 16);
    int wm = wave / WGN, wn = wave - wm * WGN;
    int wmo = wm * (MI * 16);
    int wno = wn * (NI * 16);

    f32x4 acc[MI][NI];
#pragma unroll
    for (int mi = 0; mi < MI; ++mi)
#pragma unroll
        for (int ni = 0; ni < NI; ++ni)
            acc[mi][ni] = (f32x4){0.f, 0.f, 0.f, 0.f};

    constexpr int AIT = (BM * BK / 8) / 256;
    constexpr int BIT = (BN * BK / 8) / 256;

    for (int k0 = 0; k0 < kcount; k0 += BK) {
        int kb = kstart + k0;
#pragma unroll
        for (int i = 0; i < AIT; ++i) {
            int p   = i * 256 + tid;
            int row = p >> 3;
            int kc  = (p & 7) ^ (row & 7);
            const u16* gp = Ab + (long)(m0 + row) * lda + kb + kc * 8;
            gload16(gp, (char*)As + (size_t)(i * 256 + wave * 64) * 16);
        }
#pragma unroll
        for (int i = 0; i < BIT; ++i) {
            int p   = i * 256 + tid;
            int row = p >> 3;
            int kc  = (p & 7) ^ (row & 7);
            const u16* gp = Bb + (long)(n0 + row) * ldb + kb + kc * 8;
            gload16(gp, (char*)Bs + (size_t)(i * 256 + wave * 64) * 16);
        }
        asm volatile("s_waitcnt vmcnt(0)");
        __syncthreads();

        const char* Ac = (const char*)As;
        const char* Bc = (const char*)Bs;
#pragma unroll
        for (int kh = 0; kh < 2; ++kh) {
            bf16x8 af[MI], bfr[NI];
            int kby = kh * 64 + ((lane >> 4) << 4);
#pragma unroll
            for (int mi = 0; mi < MI; ++mi) {
                int r = wmo + mi * 16 + (lane & 15);
                af[mi] = *(const bf16x8*)(Ac + r * 128 + (kby ^ ((r & 7) << 4)));
            }
#pragma unroll
            for (int ni = 0; ni < NI; ++ni) {
                int r = wno + ni * 16 + (lane & 15);
                bfr[ni] = *(const bf16x8*)(Bc + r * 128 + (kby ^ ((r & 7) << 4)));
            }
#pragma unroll
            for (int mi = 0; mi < MI; ++mi)
#pragma unroll
                for (int ni = 0; ni < NI; ++ni)
                    acc[mi][ni] = __builtin_amdgcn_mfma_f32_16x16x32_bf16(
                        af[mi], bfr[ni], acc[mi][ni], 0, 0, 0);
        }
        __syncthreads();
    }

    long cb = zb * bsC1 + zh * bsC2 + (long)pair * pairC;
#pragma unroll
    for (int mi = 0; mi < MI; ++mi) {
#pragma unroll
        for (int ni = 0; ni < NI; ++ni) {
            int col = n0 + wno + ni * 16 + (lane & 15);
            float bv = bias ? bias[col] : 0.f;
#pragma unroll
            for (int j = 0; j < 4; ++j) {
                int row = m0 + wmo + mi * 16 + ((lane >> 4) << 2) + j;
                float v = acc[mi][ni][j] * alpha + bv;
                if (ACT) v = fmaxf(v, 0.f);
                long idx = (long)row * ldc + col + cb;
                if (OUTBF16) ((u16*)Cv)[idx] = f2bf(v);
                else         ((float*)Cv)[idx] = v;
            }
        }
    }
}

// ---------------------------------------------------------------------------
// GEMM (BM templated, BN=256) with fused LayerNorm epilogue.
// MODE 0 (BM=64): qkv proj; seg selects q/k/v; seg0->qb, seg1->kb+kT, seg2->vT.
// MODE 1 (BM=32): DUAL GEMM: A@BT (K) + A2@BT2 (K2) + bias+bias2 + sb residual
//                 + LN -> outRM (h1b).  [short GEMM folded in via concat-K]
// MODE 2 (BM=32): f2 + LN(h1b + f2out) -> outF (fp32 final)
// ---------------------------------------------------------------------------
template<int MODE, int BM>
__global__ __launch_bounds__(256) void gemm_ln_k(
    const u16* __restrict__ A, const u16* __restrict__ BT,
    const float* __restrict__ bias, int K, int lda,
    const u16* __restrict__ A2, const u16* __restrict__ BT2,
    const float* __restrict__ bias2, int K2,
    const float* __restrict__ lg0, const float* __restrict__ lb0,
    const float* __restrict__ lg1, const float* __restrict__ lb1,
    const float* __restrict__ lg2, const float* __restrict__ lb2,
    const u16* __restrict__ resB0,
    u16* __restrict__ outRM, u16* __restrict__ outRM2,
    u16* __restrict__ outT, float* __restrict__ outF)
{
    constexpr int BK = 64;
    constexpr int MI = BM / 16;
    constexpr int ABYTES = BM * 128;
    constexpr int NPASS = (MODE == 1) ? 2 : 1;
    __shared__ char smem[ABYTES + 32768];
    __shared__ float redS[BM][4], redQ[BM][4];
    u16* Asm = (u16*)smem;
    u16* Bsm = (u16*)(smem + ABYTES);

    int seg = blockIdx.x;
    int m0 = blockIdx.y * BM;
    int n0 = seg * 256;
    int tid = threadIdx.x, wave = tid >> 6, lane = tid & 63;
    int c = lane & 15, g = lane >> 4;

    f32x4 acc[MI][4];
#pragma unroll
    for (int mi = 0; mi < MI; ++mi)
#pragma unroll
        for (int ni = 0; ni < 4; ++ni)
            acc[mi][ni] = (f32x4){0.f, 0.f, 0.f, 0.f};

    constexpr int AIT = (BM * BK / 8) / 256;

#pragma unroll 1
    for (int pass = 0; pass < NPASS; ++pass) {
        const u16* Ap  = (pass == 0) ? A  : A2;
        const u16* Bp  = (pass == 0) ? BT : BT2;
        int Kp   = (pass == 0) ? K : K2;
        int ldap = (pass == 0) ? lda : K2;

        for (int k0 = 0; k0 < Kp; k0 += BK) {
#pragma unroll
            for (int i = 0; i < AIT; ++i) {
                int p   = i * 256 + tid;
                int row = p >> 3;
                int kc  = (p & 7) ^ (row & 7);
                gload16(Ap + (long)(m0 + row) * ldap + k0 + kc * 8,
                        smem + (size_t)(i * 256 + wave * 64) * 16);
            }
#pragma unroll
            for (int i = 0; i < 8; ++i) {           // B: 256x64
                int p   = i * 256 + tid;
                int row = p >> 3;
                int kc  = (p & 7) ^ (row & 7);
                gload16(Bp + (long)(n0 + row) * Kp + k0 + kc * 8,
                        smem + ABYTES + (size_t)(i * 256 + wave * 64) * 16);
            }
            asm volatile("s_waitcnt vmcnt(0)");
            __syncthreads();

            const char* Ac = (const char*)Asm;
            const char* Bc = (const char*)Bsm;
#pragma unroll
            for (int kh = 0; kh < 2; ++kh) {
                bf16x8 af[MI], bfr[4];
                int kby = kh * 64 + (g << 4);
#pragma unroll
                for (int mi = 0; mi < MI; ++mi) {
                    int r = mi * 16 + c;
                    af[mi] = *(const bf16x8*)(Ac + r * 128 + (kby ^ ((r & 7) << 4)));
                }
#pragma unroll
                for (int ni = 0; ni < 4; ++ni) {
                    int r = wave * 64 + ni * 16 + c;
                    bfr[ni] = *(const bf16x8*)(Bc + r * 128 + (kby ^ ((r & 7) << 4)));
                }
#pragma unroll
                for (int mi = 0; mi < MI; ++mi)
#pragma unroll
                    for (int ni = 0; ni < 4; ++ni)
                        acc[mi][ni] = __builtin_amdgcn_mfma_f32_16x16x32_bf16(
                            af[mi], bfr[ni], acc[mi][ni], 0, 0, 0);
            }
            __syncthreads();
        }
    }

    // ---- bias + residuals ----
#pragma unroll
    for (int mi = 0; mi < MI; ++mi)
#pragma unroll
        for (int ni = 0; ni < 4; ++ni) {
            int colL = wave * 64 + ni * 16 + c;
            float bv = bias[n0 + colL];
            if (MODE == 1) bv += bias2[colL];
#pragma unroll
            for (int j = 0; j < 4; ++j) {
                int row = mi * 16 + g * 4 + j;
                float v = acc[mi][ni][j] + bv;
                if (MODE == 1 || MODE == 2) {
                    long idx = (long)(m0 + row) * 256 + colL;
                    v += bf2f(resB0[idx]);
                }
                acc[mi][ni][j] = v;
            }
        }

    // ---- per-row sum / sumsq ----
#pragma unroll
    for (int mi = 0; mi < MI; ++mi)
#pragma unroll
        for (int j = 0; j < 4; ++j) {
            float s1 = 0.f, q1 = 0.f;
#pragma unroll
            for (int ni = 0; ni < 4; ++ni) {
                float v = acc[mi][ni][j];
                s1 += v; q1 += v * v;
            }
#pragma unroll
            for (int m = 1; m <= 8; m <<= 1) {
                s1 += __shfl_xor(s1, m);
                q1 += __shfl_xor(q1, m);
            }
            if (c == 0) {
                int row = mi * 16 + g * 4 + j;
                redS[row][wave] = s1;
                redQ[row][wave] = q1;
            }
        }
    __syncthreads();

    const float* gam;
    const float* bet;
    if (MODE == 0) {
        gam = (seg == 0) ? lg0 : (seg == 1) ? lg1 : lg2;
        bet = (seg == 0) ? lb0 : (seg == 1) ? lb1 : lb2;
    } else { gam = lg0; bet = lb0; }

    u16* T = (u16*)smem;   // [256][65] bf16 — only MODE 0 (BM=64); reads done

    float gv[4], bv2[4];
#pragma unroll
    for (int ni = 0; ni < 4; ++ni) {
        int colL = wave * 64 + ni * 16 + c;
        gv[ni] = gam[colL];
        bv2[ni] = bet[colL];
    }

#pragma unroll
    for (int mi = 0; mi < MI; ++mi)
#pragma unroll
        for (int j = 0; j < 4; ++j) {
            int row = mi * 16 + g * 4 + j;
            float S = redS[row][0] + redS[row][1] + redS[row][2] + redS[row][3];
            float Q = redQ[row][0] + redQ[row][1] + redQ[row][2] + redQ[row][3];
            float mu = S * (1.0f / 256.f);
            float var = Q * (1.0f / 256.f) - mu * mu;
            float rs = rsqrtf(var + 1e-5f);
#pragma unroll
            for (int ni = 0; ni < 4; ++ni) {
                int colL = wave * 64 + ni * 16 + c;
                float o = (acc[mi][ni][j] - mu) * rs * gv[ni] + bv2[ni];
                long idx = (long)(m0 + row) * 256 + colL;
                if (MODE == 0) {
                    u16 ob = f2bf(o);
                    if (seg == 0)      outRM[idx]  = ob;
                    else if (seg == 1) { outRM2[idx] = ob; T[colL * 65 + row] = ob; }
                    else               T[colL * 65 + row] = ob;
                } else if (MODE == 1) {
                    outRM[idx] = f2bf(o);
                } else {
                    outF[idx] = o;
                }
            }
        }

    if (MODE == 0 && seg >= 1) {
        __syncthreads();
        int b = m0 >> 11;
        int l0 = m0 & 2047;
        u16* dst = outT + ((seg == 2) ? 2097152 : 0)
                 + (long)b * 524288 + (long)tid * 2048 + l0;
        const u16* src = T + tid * 65;
#pragma unroll
        for (int i = 0; i < 8; ++i) {
            u16 tmp[8];
#pragma unroll
            for (int k2 = 0; k2 < 8; ++k2) tmp[k2] = src[i * 8 + k2];
            *(uint4*)(dst + i * 8) = *(uint4*)tmp;
        }
    }
}

// ---------------------------------------------------------------------------
// Fused long-range attention (verified round 2)
// ---------------------------------------------------------------------------
__global__ __launch_bounds__(256) void attn_k(
    const u16* __restrict__ qb, const u16* __restrict__ kcb,
    const u16* __restrict__ vcT, u16* __restrict__ lngb)
{
    __shared__ u16 Ps[64 * 128];

    int bh = blockIdx.y;
    int b = bh >> 2, h = bh & 3;
    int l0 = blockIdx.x * 64;
    int tid = threadIdx.x, wave = tid >> 6, lane = tid & 63;
    int c = lane & 15, g = lane >> 4;

    const u16* kc = kcb + (long)b * (RR * DV) + h * 64;
    const u16* qg = qb + ((long)(b * LSEQ + l0)) * DV + h * 64;
    const u16* vg = vcT + ((long)b * DV + h * 64) * RR;

    f32x4 acc[8];
#pragma unroll
    for (int mi = 0; mi < 8; ++mi) acc[mi] = (f32x4){0.f, 0.f, 0.f, 0.f};

#pragma unroll
    for (int kh = 0; kh < 2; ++kh) {
        bf16x8 bq = *(const bf16x8*)(qg + (long)(wave * 16 + c) * DV + kh * 32 + g * 8);
#pragma unroll
        for (int mi = 0; mi < 8; ++mi) {
            bf16x8 af = *(const bf16x8*)(kc + (long)(mi * 16 + c) * DV + kh * 32 + g * 8);
            acc[mi] = __builtin_amdgcn_mfma_f32_16x16x32_bf16(af, bq, acc[mi], 0, 0, 0);
        }
    }

    float mx = -INFINITY;
#pragma unroll
    for (int mi = 0; mi < 8; ++mi)
#pragma unroll
        for (int j = 0; j < 4; ++j) {
            acc[mi][j] *= 0.125f;
            mx = fmaxf(mx, acc[mi][j]);
        }
    mx = fmaxf(mx, __shfl_xor(mx, 16));
    mx = fmaxf(mx, __shfl_xor(mx, 32));
    float den = 0.f;
#pragma unroll
    for (int mi = 0; mi < 8; ++mi)
#pragma unroll
        for (int j = 0; j < 4; ++j) {
            acc[mi][j] = __expf(acc[mi][j] - mx);
            den += acc[mi][j];
        }
    den += __shfl_xor(den, 16);
    den += __shfl_xor(den, 32);
    float inv = 1.0f / den;

    int l = wave * 16 + c;
#pragma unroll
    for (int mi = 0; mi < 8; ++mi) {
        short4 sv;
        sv.x = (short)f2bf(acc[mi][0] * inv);
        sv.y = (short)f2bf(acc[mi][1] * inv);
        sv.z = (short)f2bf(acc[mi][2] * inv);
        sv.w = (short)f2bf(acc[mi][3] * inv);
        int byte = l * 256 + ((mi * 32 + g * 8) ^ ((l & 7) << 4));
        *(short4*)((char*)Ps + byte) = sv;
    }
    __syncthreads();

    f32x4 a2[4];
#pragma unroll
    for (int ni = 0; ni < 4; ++ni) a2[ni] = (f32x4){0.f, 0.f, 0.f, 0.f};
#pragma unroll
    for (int kb = 0; kb < 4; ++kb) {
        int kby = kb * 64 + (g << 4);
        bf16x8 pa = *(const bf16x8*)((char*)Ps + l * 256 + (kby ^ ((l & 7) << 4)));
#pragma unroll
        for (int ni = 0; ni < 4; ++ni) {
            bf16x8 vf = *(const bf16x8*)(vg + (long)(ni * 16 + c) * RR + kb * 32 + g * 8);
            a2[ni] = __builtin_amdgcn_mfma_f32_16x16x32_bf16(pa, vf, a2[ni], 0, 0, 0);
        }
    }
#pragma unroll
    for (int ni = 0; ni < 4; ++ni)
#pragma unroll
        for (int j = 0; j < 4; ++j) {
            int lr = wave * 16 + g * 4 + j;
            int dh = ni * 16 + c;
            lngb[((long)(b * LSEQ + l0 + lr)) * DV + h * 64 + dh] = f2bf(a2[ni][j]);
        }
}

// ---------------------------------------------------------------------------
// Preprocessing: weight transposes + s cast + bias concat
// ---------------------------------------------------------------------------
struct WTD { const float* src; u16* dst; int K, N, toff; };
struct WTA { WTD d[9]; };

__global__ __launch_bounds__(256) void prep_k(WTA a,
    const float* __restrict__ sin, u16* __restrict__ sout,
    const float* qb_, const float* kb_, const float* vb_,
    float* qkvb)
{
    int bid = blockIdx.x;
    if (bid < 1312) {
        int di = 0;
#pragma unroll
        for (int i = 1; i < 9; ++i) if (bid >= a.d[i].toff) di = i;
        const float* src = a.d[di].src;
        u16* dst = a.d[di].dst;
        int K = a.d[di].K, N = a.d[di].N;
        int tix = bid - a.d[di].toff;
        int nx = N >> 5;
        int tn = tix % nx, tk = tix / nx;
        int n0 = tn * 32, k0 = tk * 32;

        __shared__ float t[32][33];
        int tx = threadIdx.x & 31, ty = threadIdx.x >> 5;
#pragma unroll
        for (int i = 0; i < 32; i += 8)
            t[ty + i][tx] = src[(long)(k0 + ty + i) * N + n0 + tx];
        __syncthreads();
#pragma unroll
        for (int i = 0; i < 32; i += 8)
            dst[(long)(n0 + ty + i) * K + k0 + tx] = f2bf(t[tx][ty + i]);
    } else if (bid < 3360) {
        int i = ((bid - 1312) * 256 + threadIdx.x) * 4;
        float4 v = *(const float4*)(sin + i);
        sout[i]     = f2bf(v.x);
        sout[i + 1] = f2bf(v.y);
        sout[i + 2] = f2bf(v.z);
        sout[i + 3] = f2bf(v.w);
    } else {
        int i = threadIdx.x;
#pragma unroll
        for (int rep = 0; rep < 3; ++rep) {
            int j = i + rep * 256;
            qkvb[j] = (j < 256) ? qb_[j] : ((j < 512) ? kb_[j - 256] : vb_[j - 512]);
        }
    }
}

// ---------------------------------------------------------------------------
// GAT attention logits: wave-per-row, shfl reduce
// ---------------------------------------------------------------------------
__global__ __launch_bounds__(256) void gat_att_k(
    const u16* __restrict__ h, const float* __restrict__ att_src,
    const float* __restrict__ att_dst, float* __restrict__ a_src,
    float* __restrict__ a_dst)
{
    int row  = blockIdx.x * 4 + (threadIdx.x >> 6);
    int lane = threadIdx.x & 63;
    int c0   = lane * 16;
    int head = lane >> 4;

    float as[16], ad[16];
#pragma unroll
    for (int i = 0; i < 16; ++i) { as[i] = att_src[c0 + i]; ad[i] = att_dst[c0 + i]; }

    const u16* hr = h + (long)row * (HH * DV) + c0;
    bf16x8 v0 = *(const bf16x8*)(hr);
    bf16x8 v1 = *(const bf16x8*)(hr + 8);
    float ps = 0.f, pd = 0.f;
#pragma unroll
    for (int i = 0; i < 8; ++i) {
        float f0 = bf2f((u16)v0[i]), f1 = bf2f((u16)v1[i]);
        ps += f0 * as[i] + f1 * as[i + 8];
        pd += f0 * ad[i] + f1 * ad[i + 8];
    }
#pragma unroll
    for (int m = 1; m <= 8; m <<= 1) {
        ps += __shfl_xor(ps, m);
        pd += __shfl_xor(pd, m);
    }
    if ((lane & 15) == 0) {
        a_src[(long)row * HH + head] = ps;
        a_dst[(long)row * HH + head] = pd;
    }
}

// ---------------------------------------------------------------------------
// CSR build over dst: single block, 1024 threads, LDS count+scan+fill.
// ---------------------------------------------------------------------------
__global__ __launch_bounds__(1024) void csr_build_k(
    const int* __restrict__ ei, int* __restrict__ off, int* __restrict__ bucket)
{
    __shared__ int cnt[2048];
    __shared__ int wsum[1024];
    int tid = threadIdx.x;
    cnt[tid] = 0; cnt[tid + 1024] = 0;
    __syncthreads();
    for (int i = tid; i < ETOT; i += 1024) {
        int dst = (i < EE) ? ei[EE + i] : (i - EE);
        atomicAdd(&cnt[dst], 1);
    }
    __syncthreads();
    int a = cnt[tid * 2], b = cnt[tid * 2 + 1];
    wsum[tid] = a + b;
    __syncthreads();
    for (int st = 1; st < 1024; st <<= 1) {
        int v = (tid >= st) ? wsum[tid - st] : 0;
        __syncthreads();
        wsum[tid] += v;
        __syncthreads();
    }
    int pre = (tid == 0) ? 0 : wsum[tid - 1];
    off[tid * 2]     = pre;
    off[tid * 2 + 1] = pre + a;
    if (tid == 1023) off[2048] = wsum[1023];
    __syncthreads();
    cnt[tid * 2]     = pre;         // cursor = off
    cnt[tid * 2 + 1] = pre + a;
    __syncthreads();
    for (int i = tid; i < ETOT; i += 1024) {
        int dst = (i < EE) ? ei[EE + i] : (i - EE);
        int p = atomicAdd(&cnt[dst], 1);
        bucket[p] = i;
    }
}

// ---------------------------------------------------------------------------
// GAT scatter-softmax + aggregate: ONE WAVE PER (b,n), single edge pass.
// XCD-locality swizzle: batch b -> XCD pair {2b,2b+1}.
// ---------------------------------------------------------------------------
__global__ __launch_bounds__(256) void gat_gather_k(
    const u16* __restrict__ h, const int* __restrict__ ei,
    const int* __restrict__ off, const int* __restrict__ bucket,
    const float* __restrict__ a_src, const float* __restrict__ a_dst,
    const float* __restrict__ gat_b, u16* __restrict__ out)
{
    int wv = threadIdx.x >> 6, lane = threadIdx.x & 63;
    int id = blockIdx.x;               // 0..2047
    int jg = id >> 3, r8 = id & 7;
    int b  = r8 >> 1;
    int n  = (jg * 2 + (r8 & 1)) * 4 + wv;
    int beg = off[n], deg = off[n + 1] - beg;

    __shared__ int   src_sh[4][64];
    __shared__ float ex_sh[4][64][4];

    const float* asrc_b = a_src + (long)b * LSEQ * HH;
    const float4 ad4 = *(const float4*)(a_dst + ((long)b * LSEQ + n) * HH);
    float adst[4] = { ad4.x, ad4.y, ad4.z, ad4.w };

    int hd = lane >> 4;
    const u16* hb = h + (long)b * LSEQ * (HH * DV) + lane * 16;
    float acc[16];
#pragma unroll
    for (int i = 0; i < 16; ++i) acc[i] = 0.f;
    float sm[4] = { 0.f, 0.f, 0.f, 0.f };

    for (int c0 = 0; c0 < deg; c0 += 64) {
        int idx = c0 + lane;
        if (idx < deg) {
            int eid = bucket[beg + idx];
            int src = (eid < EE) ? ei[eid] : (eid - EE);
            src_sh[wv][lane] = src;
            float4 as4 = *(const float4*)(asrc_b + (long)src * HH);
            float as[4] = { as4.x, as4.y, as4.z, as4.w };
#pragma unroll
            for (int hh = 0; hh < 4; ++hh) {
                float e = as[hh] + adst[hh];
                e = (e >= 0.f) ? e : 0.2f * e;
                float ex = __expf(e);
                ex_sh[wv][lane][hh] = ex;
                sm[hh] += ex;
            }
        }
        int cn = deg - c0; if (cn > 64) cn = 64;
#pragma unroll 2
        for (int j = 0; j < cn; ++j) {
            int src = src_sh[wv][j];
            float al = ex_sh[wv][j][hd];
            const u16* p = hb + (long)src * (HH * DV);
            bf16x8 v0 = *(const bf16x8*)p;
            bf16x8 v1 = *(const bf16x8*)(p + 8);
#pragma unroll
            for (int i = 0; i < 8; ++i) {
                acc[i]     += al * bf2f((u16)v0[i]);
                acc[i + 8] += al * bf2f((u16)v1[i]);
            }
        }
    }

#pragma unroll
    for (int hh = 0; hh < 4; ++hh)
#pragma unroll
        for (int m = 32; m >= 1; m >>= 1)
            sm[hh] += __shfl_xor(sm[hh], m);
    float inv = 1.0f / sm[hd];

    u16 o16[16];
    const float* gb = gat_b + lane * 16;
#pragma unroll
    for (int i = 0; i < 16; ++i) o16[i] = f2bf(acc[i] * inv + gb[i]);
    uint4* op = (uint4*)(out + ((long)b * LSEQ + n) * (HH * DV) + lane * 16);
    op[0] = ((uint4*)o16)[0];
    op[1] = ((uint4*)o16)[1];
}

// pm softmax over L: single global read pass
__global__ __launch_bounds__(256) void colsoftmax_k(const float* __restrict__ pm,
                                                    u16* __restrict__ pmT)
{
    int r = blockIdx.x;
    int b = blockIdx.y;
    int tid = threadIdx.x, wave = tid >> 6, lane = tid & 63;
    const float* base = pm + (long)b * LSEQ * RR + r;
    u16* obase = pmT + ((long)b * RR + r) * LSEQ;

    float x[8];
#pragma unroll
    for (int i = 0; i < 8; ++i) x[i] = base[(long)(tid + i * 256) * RR];

    __shared__ float red[4];
    __shared__ float m_sh, d_sh;
    float mx = x[0];
#pragma unroll
    for (int i = 1; i < 8; ++i) mx = fmaxf(mx, x[i]);
#pragma unroll
    for (int m = 32; m >= 1; m >>= 1) mx = fmaxf(mx, __shfl_xor(mx, m));
    if (lane == 0) red[wave] = mx;
    __syncthreads();
    if (tid == 0) m_sh = fmaxf(fmaxf(red[0], red[1]), fmaxf(red[2], red[3]));
    __syncthreads();
    float m = m_sh;
    float sm = 0.f;
#pragma unroll
    for (int i = 0; i < 8; ++i) { x[i] = __expf(x[i] - m); sm += x[i]; }
#pragma unroll
    for (int mm = 32; mm >= 1; mm >>= 1) sm += __shfl_xor(sm, mm);
    if (lane == 0) red[wave] = sm;
    __syncthreads();
    if (tid == 0) d_sh = red[0] + red[1] + red[2] + red[3];
    __syncthreads();
    float inv = 1.0f / d_sh;
#pragma unroll
    for (int i = 0; i < 8; ++i) obase[tid + i * 256] = f2bf(x[i] * inv);
}

// sum 16 split-K partials -> bf16 kvcb, and (pair==1) transposed vcT
__global__ __launch_bounds__(256) void reduce_kvc_k(
    const float* __restrict__ part, u16* __restrict__ kvcb, u16* __restrict__ vcT)
{
    int pb = blockIdx.z;
    int pair = pb >> 2, b = pb & 3;
    int r0 = blockIdx.y * 32, d0 = blockIdx.x * 64;
    int tid = threadIdx.x;
    __shared__ float t[32][65];
    const float* pp = part + (long)pb * (16 * 32768);
    int r = tid >> 6;
    int d = tid & 63;
#pragma unroll
    for (int i = 0; i < 8; ++i) {
        int rr = r0 + r + i * 4;
        float s = 0.f;
#pragma unroll
        for (int sp = 0; sp < 16; ++sp)
            s += pp[(long)sp * 32768 + rr * 256 + d0 + d];
        kvcb[(long)pb * 32768 + rr * 256 + d0 + d] = f2bf(s);
        t[r + i * 4][d] = s;
    }
    if (pair == 0) return;
    __syncthreads();
    int dd = tid >> 2, rb = (tid & 3) * 8;
    u16 o8[8];
#pragma unroll
    for (int k = 0; k < 8; ++k) o8[k] = f2bf(t[rb + k][dd]);
    *(uint4*)(vcT + ((long)(b * 256 + d0 + dd)) * 128 + r0 + rb) = *(uint4*)o8;
}

// ---------------------------------------------------------------------------
extern "C" void kernel_launch(void* const* d_in, const int* in_sizes, int n_in,
                              void* d_out, int out_size, void* d_ws, size_t ws_size,
                              hipStream_t stream)
{
    const float* s        = (const float*)d_in[0];
    const float* gat_W    = (const float*)d_in[1];
    const float* att_src  = (const float*)d_in[2];
    const float* att_dst  = (const float*)d_in[3];
    const float* gat_b    = (const float*)d_in[4];
    const float* short_W  = (const float*)d_in[5];
    const float* short_b  = (const float*)d_in[6];
    const float* q_W      = (const float*)d_in[7];
    const float* q_b      = (const float*)d_in[8];
    const float* k_W      = (const float*)d_in[9];
    const float* k_b      = (const float*)d_in[10];
    const float* v_W      = (const float*)d_in[11];
    const float* v_b      = (const float*)d_in[12];
    const float* o_W      = (const float*)d_in[13];
    const float* o_b      = (const float*)d_in[14];
    const float* p_W      = (const float*)d_in[15];
    const float* p_b      = (const float*)d_in[16];
    const float* lnq_g    = (const float*)d_in[17];
    const float* lnq_b    = (const float*)d_in[18];
    const float* lnk_g    = (const float*)d_in[19];
    const float* lnk_b    = (const float*)d_in[20];
    const float* lnv_g    = (const float*)d_in[21];
    const float* lnv_b    = (const float*)d_in[22];
    const float* ln1_g    = (const float*)d_in[23];
    const float* ln1_b    = (const float*)d_in[24];
    const float* ln2_g    = (const float*)d_in[25];
    const float* ln2_b    = (const float*)d_in[26];
    const float* f1_W     = (const float*)d_in[27];
    const float* f1_b     = (const float*)d_in[28];
    const float* f2_W     = (const float*)d_in[29];
    const float* f2_b     = (const float*)d_in[30];
    const int*   ei       = (const int*)d_in[31];
    float* out = (float*)d_out;

    const size_t MB = 1024 * 1024;
    char* W = (char*)d_ws;
    u16*   sb      = (u16*)(W);                         // 4MB
    u16*   gatT    = (u16*)(W + 4*MB);                  // 512KB
    u16*   shortT  = (u16*)(W + 4*MB + 524288);         // 512KB
    u16*   qkvT    = (u16*)(W + 4*MB + 1048576);        // 384KB
    u16*   oT      = (u16*)(W + 4*MB + 1441792);        // 128KB
    u16*   pT      = (u16*)(W + 4*MB + 1572864);        // 64KB
    u16*   f1T     = (u16*)(W + 4*MB + 1638400);        // 512KB
    u16*   f2T     = (u16*)(W + 4*MB + 2162688);        // 512KB
    float* qkvb    = (float*)(W + 4*MB + 2686976);      // 3KB
    int*   ioff    = (int*)(W + 4*MB + 2690048);        // 2049
    int*   ibucket = (int*)(W + 4*MB + 2707456);        // 34816
    u16*   h       = (u16*)(W + 8*MB);                  // 16MB
    u16*   ffh     = (u16*)(W + 8*MB);                  // alias h (16MB)
    u16*   gat_out = (u16*)(W + 24*MB);                 // 16MB
    u16*   h1b     = (u16*)(W + 40*MB);                 // 4MB
    float* pmraw   = (float*)(W + 48*MB);               // 4MB (dead after colsoftmax)
    float* part    = (float*)(W + 48*MB);               // alias 16MB (dead after reduce_kvc)
    u16*   lngb    = (u16*)(W + 48*MB);                 // alias 4MB (after part dead)
    u16*   qb      = (u16*)(W + 72*MB);                 // 4MB
    u16*   kb      = (u16*)(W + 76*MB);                 // 4MB
    u16*   kvT     = (u16*)(W + 84*MB);                 // 8MB [2 pair][4 b][256][2048]
    u16*   pmT     = (u16*)(W + 92*MB);                 // 2MB
    u16*   kvcb    = (u16*)(W + 94*MB);                 // 512KB
    u16*   vcT     = (u16*)(W + 94*MB + 524288);        // 256KB
    float* a_src   = (float*)(W + 95*MB);               // 128KB
    float* a_dst   = (float*)(W + 95*MB + 131072);      // 128KB

    const int ML = BB * LSEQ;  // 8192

    // ---- prep: weights -> bf16^T, s cast, bias concat ----
    WTA wa;
    wa.d[0] = { gat_W,   gatT,            256, 1024, 0    };
    wa.d[1] = { short_W, shortT,         1024,  256, 256  };
    wa.d[2] = { q_W,     qkvT,            256,  256, 512  };
    wa.d[3] = { k_W,     qkvT + 65536,    256,  256, 576  };
    wa.d[4] = { v_W,     qkvT + 131072,   256,  256, 640  };
    wa.d[5] = { o_W,     oT,              256,  256, 704  };
    wa.d[6] = { p_W,     pT,              256,  128, 768  };
    wa.d[7] = { f1_W,    f1T,             256, 1024, 800  };
    wa.d[8] = { f2_W,    f2T,            1024,  256, 1056 };
    prep_k<<<3361, 256, 0, stream>>>(wa, s, sb, q_b, k_b, v_b, qkvb);

    // ---- CSR (single block) ----
    csr_build_k<<<1, 1024, 0, stream>>>(ei, ioff, ibucket);

    // ---- GAT ----
    mfma_gemm_k<128, 128, 1, 0><<<dim3(8, 64, 1), 256, 0, stream>>>(
        sb, gatT, nullptr, h, ML, 1024, 256, 256, 256, 1024,
        0, 0, 0, 0, 0, 0, 1, 0, 0, 0, 0, 1.f);
    gat_att_k<<<ML / 4, 256, 0, stream>>>(h, att_src, att_dst, a_src, a_dst);
    gat_gather_k<<<2048, 256, 0, stream>>>(h, ei, ioff, ibucket,
                                           a_src, a_dst, gat_b, gat_out);

    // ---- qkv projection + fused LN(q/k/v) + k^T/v^T transposes ----
    gemm_ln_k<0, 64><<<dim3(3, 128), 256, 0, stream>>>(
        sb, qkvT, qkvb, 256, 256,
        nullptr, nullptr, nullptr, 0,
        lnq_g, lnq_b, lnk_g, lnk_b, lnv_g, lnv_b,
        nullptr, qb, kb, kvT, nullptr);

    // pm = softmax_L(k @ p_W + p_b) -> pmT bf16 [b][r][l]
    mfma_gemm_k<64, 64, 0, 0><<<dim3(2, 128, 1), 256, 0, stream>>>(
        kb, pT, p_b, pmraw, ML, 128, 256, 256, 256, 128,
        0, 0, 0, 0, 0, 0, 1, 0, 0, 0, 0, 1.f);
    colsoftmax_k<<<dim3(RR, BB), 256, 0, stream>>>(pmraw, pmT);

    // k_c/v_c via split-K (16 splits): part [pair][b][16][128][256]
    mfma_gemm_k<128, 128, 0, 0><<<dim3(2, 2, 64), 256, 0, stream>>>(
        pmT, kvT, nullptr, part, 128, 256, 2048, 2048, 2048, 256,
        262144, 0, 524288, 0, 524288, 32768, 16, 2097152, 2097152, 128, 1, 1.f);
    reduce_kvc_k<<<dim3(4, 4, 8), 256, 0, stream>>>(part, kvcb, vcT);

    // ---- fused attention ----
    attn_k<<<dim3(LSEQ / 64, BB * HH), 256, 0, stream>>>(qb, kvcb, vcT, lngb);

    // ---- DUAL: lng@o_W + gat_out@short_W + (o_b+short_b) + sb + LN1 -> h1b ----
    gemm_ln_k<1, 32><<<dim3(1, 256), 256, 0, stream>>>(
        lngb, oT, o_b, 256, 256,
        gat_out, shortT, short_b, 1024,
        ln1_g, ln1_b, nullptr, nullptr, nullptr, nullptr,
        sb, h1b, nullptr, nullptr, nullptr);

    // FFN
    mfma_gemm_k<128, 128, 1, 1><<<dim3(8, 64, 1), 256, 0, stream>>>(
        h1b, f1T, f1_b, ffh, ML, 1024, 256, 256, 256, 1024,
        0, 0, 0, 0, 0, 0, 1, 0, 0, 0, 0, 1.f);

    // ---- f2 + fused LN(h1 + ff2) -> out (fp32) ----
    gemm_ln_k<2, 32><<<dim3(1, 256), 256, 0, stream>>>(
        ffh, f2T, f2_b, 1024, 1024,
        nullptr, nullptr, nullptr, 0,
        ln2_g, ln2_b, nullptr, nullptr, nullptr, nullptr,
        h1b, nullptr, nullptr, nullptr, out);
}

// Round 16
// 195.860 us; speedup vs baseline: 1.0635x; 1.0635x over previous
//
#include <hip/hip_runtime.h>
#include <math.h>

#define BB   4
#define LSEQ 2048
#define DV   256
#define HH   4
#define RR   128
#define EE   32768
#define ETOT (EE + LSEQ)
#define FFD  1024

typedef unsigned short u16;
typedef __attribute__((ext_vector_type(8))) short bf16x8;
typedef __attribute__((ext_vector_type(4))) float f32x4;

__device__ __forceinline__ u16 f2bf(float f) {
    union { float f; unsigned u; } x; x.f = f;
    unsigned r = x.u + 0x7fff + ((x.u >> 16) & 1);
    return (u16)(r >> 16);
}
__device__ __forceinline__ float bf2f(u16 u) {
    union { unsigned u; float f; } x; x.u = ((unsigned)u) << 16;
    return x.f;
}

__device__ __forceinline__ void gload16(const void* g, void* l) {
    __builtin_amdgcn_global_load_lds(
        (const __attribute__((address_space(1))) unsigned int*)g,
        (__attribute__((address_space(3))) unsigned int*)l, 16, 0, 0);
}

// ---------------------------------------------------------------------------
// bf16 MFMA GEMM. BM in {128,64}, BN in {128,64}, BK=64. (verified)
// ---------------------------------------------------------------------------
template<int BM, int BN, int OUTBF16, int ACT>
__global__ __launch_bounds__(256) void mfma_gemm_k(
    const u16* __restrict__ A, const u16* __restrict__ BT,
    const float* __restrict__ bias, void* __restrict__ Cv,
    int M, int N, int K, int lda, int ldb, int ldc,
    long bsA1, long bsA2, long bsB1, long bsB2, long bsC1, long bsC2,
    int subH, long pairB, long pairC, int ksl, int split, float alpha)
{
    constexpr int BK = 64;
    __shared__ u16 As[BM * BK];
    __shared__ u16 Bs[BN * BK];

    int z = blockIdx.z;
    int zb = z / subH, zh = z - zb * subH;
    int mtiles = M / BM;
    int pair = blockIdx.y / mtiles;
    int mt   = blockIdx.y - pair * mtiles;

    const u16* Ab = A  + zb * bsA1 + zh * bsA2;
    const u16* Bb = BT + zb * bsB1 + zh * bsB2 + (long)pair * pairB;
    int kstart = split ? zh * ksl : 0;
    int kcount = split ? ksl : K;
    int m0 = mt * BM, n0 = blockIdx.x * BN;

    int tid  = threadIdx.x;
    int wave = tid >> 6, lane = tid & 63;
    constexpr int WGN = (BN == 128) ? 2 : 1;
    constexpr int WGM = 4 / WGN;
    constexpr int MI  = BM / (WGM * 16);
    constexpr int NI  = BN / (WGN * 16);
    int wm = wave / WGN, wn = wave - wm * WGN;
    int wmo = wm * (MI * 16);
    int wno = wn * (NI * 16);

    f32x4 acc[MI][NI];
#pragma unroll
    for (int mi = 0; mi < MI; ++mi)
#pragma unroll
        for (int ni = 0; ni < NI; ++ni)
            acc[mi][ni] = (f32x4){0.f, 0.f, 0.f, 0.f};

    constexpr int AIT = (BM * BK / 8) / 256;
    constexpr int BIT = (BN * BK / 8) / 256;

    for (int k0 = 0; k0 < kcount; k0 += BK) {
        int kb = kstart + k0;
#pragma unroll
        for (int i = 0; i < AIT; ++i) {
            int p   = i * 256 + tid;
            int row = p >> 3;
            int kc  = (p & 7) ^ (row & 7);
            const u16* gp = Ab + (long)(m0 + row) * lda + kb + kc * 8;
            gload16(gp, (char*)As + (size_t)(i * 256 + wave * 64) * 16);
        }
#pragma unroll
        for (int i = 0; i < BIT; ++i) {
            int p   = i * 256 + tid;
            int row = p >> 3;
            int kc  = (p & 7) ^ (row & 7);
            const u16* gp = Bb + (long)(n0 + row) * ldb + kb + kc * 8;
            gload16(gp, (char*)Bs + (size_t)(i * 256 + wave * 64) * 16);
        }
        asm volatile("s_waitcnt vmcnt(0)");
        __syncthreads();

        const char* Ac = (const char*)As;
        const char* Bc = (const char*)Bs;
#pragma unroll
        for (int kh = 0; kh < 2; ++kh) {
            bf16x8 af[MI], bfr[NI];
            int kby = kh * 64 + ((lane >> 4) << 4);
#pragma unroll
            for (int mi = 0; mi < MI; ++mi) {
                int r = wmo + mi * 16 + (lane & 15);
                af[mi] = *(const bf16x8*)(Ac + r * 128 + (kby ^ ((r & 7) << 4)));
            }
#pragma unroll
            for (int ni = 0; ni < NI; ++ni) {
                int r = wno + ni * 16 + (lane & 15);
                bfr[ni] = *(const bf16x8*)(Bc + r * 128 + (kby ^ ((r & 7) << 4)));
            }
#pragma unroll
            for (int mi = 0; mi < MI; ++mi)
#pragma unroll
                for (int ni = 0; ni < NI; ++ni)
                    acc[mi][ni] = __builtin_amdgcn_mfma_f32_16x16x32_bf16(
                        af[mi], bfr[ni], acc[mi][ni], 0, 0, 0);
        }
        __syncthreads();
    }

    long cb = zb * bsC1 + zh * bsC2 + (long)pair * pairC;
#pragma unroll
    for (int mi = 0; mi < MI; ++mi) {
#pragma unroll
        for (int ni = 0; ni < NI; ++ni) {
            int col = n0 + wno + ni * 16 + (lane & 15);
            float bv = bias ? bias[col] : 0.f;
#pragma unroll
            for (int j = 0; j < 4; ++j) {
                int row = m0 + wmo + mi * 16 + ((lane >> 4) << 2) + j;
                float v = acc[mi][ni][j] * alpha + bv;
                if (ACT) v = fmaxf(v, 0.f);
                long idx = (long)row * ldc + col + cb;
                if (OUTBF16) ((u16*)Cv)[idx] = f2bf(v);
                else         ((float*)Cv)[idx] = v;
            }
        }
    }
}

// ---------------------------------------------------------------------------
// GEMM (BM templated, BN=256) with fused LayerNorm epilogue.
// MODE 0 (BM=64): qkv proj; seg selects q/k/v; seg0->qb, seg1->kb+kT, seg2->vT.
// MODE 1 (BM=32): o-proj + LN(sb + short + oout) -> outRM (h1b)
// MODE 2 (BM=32): f2 + LN(h1b + f2out) -> outF (fp32 final)
// ---------------------------------------------------------------------------
template<int MODE, int BM>
__global__ __launch_bounds__(256) void gemm_ln_k(
    const u16* __restrict__ A, const u16* __restrict__ BT,
    const float* __restrict__ bias, int K, int lda,
    const float* __restrict__ lg0, const float* __restrict__ lb0,
    const float* __restrict__ lg1, const float* __restrict__ lb1,
    const float* __restrict__ lg2, const float* __restrict__ lb2,
    const u16* __restrict__ resB0, const u16* __restrict__ resB1,
    u16* __restrict__ outRM, u16* __restrict__ outRM2,
    u16* __restrict__ outT, float* __restrict__ outF)
{
    constexpr int BK = 64;
    constexpr int MI = BM / 16;
    constexpr int ABYTES = BM * 128;
    __shared__ char smem[ABYTES + 32768];
    __shared__ float redS[BM][4], redQ[BM][4];
    u16* Asm = (u16*)smem;
    u16* Bsm = (u16*)(smem + ABYTES);

    int seg = blockIdx.x;
    int m0 = blockIdx.y * BM;
    int n0 = seg * 256;
    int tid = threadIdx.x, wave = tid >> 6, lane = tid & 63;
    int c = lane & 15, g = lane >> 4;

    f32x4 acc[MI][4];
#pragma unroll
    for (int mi = 0; mi < MI; ++mi)
#pragma unroll
        for (int ni = 0; ni < 4; ++ni)
            acc[mi][ni] = (f32x4){0.f, 0.f, 0.f, 0.f};

    constexpr int AIT = (BM * BK / 8) / 256;

    for (int k0 = 0; k0 < K; k0 += BK) {
#pragma unroll
        for (int i = 0; i < AIT; ++i) {
            int p   = i * 256 + tid;
            int row = p >> 3;
            int kc  = (p & 7) ^ (row & 7);
            gload16(A + (long)(m0 + row) * lda + k0 + kc * 8,
                    smem + (size_t)(i * 256 + wave * 64) * 16);
        }
#pragma unroll
        for (int i = 0; i < 8; ++i) {           // B: 256x64
            int p   = i * 256 + tid;
            int row = p >> 3;
            int kc  = (p & 7) ^ (row & 7);
            gload16(BT + (long)(n0 + row) * K + k0 + kc * 8,
                    smem + ABYTES + (size_t)(i * 256 + wave * 64) * 16);
        }
        asm volatile("s_waitcnt vmcnt(0)");
        __syncthreads();

        const char* Ac = (const char*)Asm;
        const char* Bc = (const char*)Bsm;
#pragma unroll
        for (int kh = 0; kh < 2; ++kh) {
            bf16x8 af[MI], bfr[4];
            int kby = kh * 64 + (g << 4);
#pragma unroll
            for (int mi = 0; mi < MI; ++mi) {
                int r = mi * 16 + c;
                af[mi] = *(const bf16x8*)(Ac + r * 128 + (kby ^ ((r & 7) << 4)));
            }
#pragma unroll
            for (int ni = 0; ni < 4; ++ni) {
                int r = wave * 64 + ni * 16 + c;
                bfr[ni] = *(const bf16x8*)(Bc + r * 128 + (kby ^ ((r & 7) << 4)));
            }
#pragma unroll
            for (int mi = 0; mi < MI; ++mi)
#pragma unroll
                for (int ni = 0; ni < 4; ++ni)
                    acc[mi][ni] = __builtin_amdgcn_mfma_f32_16x16x32_bf16(
                        af[mi], bfr[ni], acc[mi][ni], 0, 0, 0);
        }
        __syncthreads();
    }

    // ---- bias + residuals ----
#pragma unroll
    for (int mi = 0; mi < MI; ++mi)
#pragma unroll
        for (int ni = 0; ni < 4; ++ni) {
            int colL = wave * 64 + ni * 16 + c;
            float bv = bias[n0 + colL];
#pragma unroll
            for (int j = 0; j < 4; ++j) {
                int row = mi * 16 + g * 4 + j;
                float v = acc[mi][ni][j] + bv;
                if (MODE == 1) {
                    long idx = (long)(m0 + row) * 256 + colL;
                    v += bf2f(resB0[idx]) + bf2f(resB1[idx]);
                }
                if (MODE == 2) {
                    long idx = (long)(m0 + row) * 256 + colL;
                    v += bf2f(resB0[idx]);
                }
                acc[mi][ni][j] = v;
            }
        }

    // ---- per-row sum / sumsq ----
#pragma unroll
    for (int mi = 0; mi < MI; ++mi)
#pragma unroll
        for (int j = 0; j < 4; ++j) {
            float s1 = 0.f, q1 = 0.f;
#pragma unroll
            for (int ni = 0; ni < 4; ++ni) {
                float v = acc[mi][ni][j];
                s1 += v; q1 += v * v;
            }
#pragma unroll
            for (int m = 1; m <= 8; m <<= 1) {
                s1 += __shfl_xor(s1, m);
                q1 += __shfl_xor(q1, m);
            }
            if (c == 0) {
                int row = mi * 16 + g * 4 + j;
                redS[row][wave] = s1;
                redQ[row][wave] = q1;
            }
        }
    __syncthreads();

    const float* gam;
    const float* bet;
    if (MODE == 0) {
        gam = (seg == 0) ? lg0 : (seg == 1) ? lg1 : lg2;
        bet = (seg == 0) ? lb0 : (seg == 1) ? lb1 : lb2;
    } else { gam = lg0; bet = lb0; }

    u16* T = (u16*)smem;   // [256][65] bf16 — only MODE 0 (BM=64); reads done

    float gv[4], bv2[4];
#pragma unroll
    for (int ni = 0; ni < 4; ++ni) {
        int colL = wave * 64 + ni * 16 + c;
        gv[ni] = gam[colL];
        bv2[ni] = bet[colL];
    }

#pragma unroll
    for (int mi = 0; mi < MI; ++mi)
#pragma unroll
        for (int j = 0; j < 4; ++j) {
            int row = mi * 16 + g * 4 + j;
            float S = redS[row][0] + redS[row][1] + redS[row][2] + redS[row][3];
            float Q = redQ[row][0] + redQ[row][1] + redQ[row][2] + redQ[row][3];
            float mu = S * (1.0f / 256.f);
            float var = Q * (1.0f / 256.f) - mu * mu;
            float rs = rsqrtf(var + 1e-5f);
#pragma unroll
            for (int ni = 0; ni < 4; ++ni) {
                int colL = wave * 64 + ni * 16 + c;
                float o = (acc[mi][ni][j] - mu) * rs * gv[ni] + bv2[ni];
                long idx = (long)(m0 + row) * 256 + colL;
                if (MODE == 0) {
                    u16 ob = f2bf(o);
                    if (seg == 0)      outRM[idx]  = ob;
                    else if (seg == 1) { outRM2[idx] = ob; T[colL * 65 + row] = ob; }
                    else               T[colL * 65 + row] = ob;
                } else if (MODE == 1) {
                    outRM[idx] = f2bf(o);
                } else {
                    outF[idx] = o;
                }
            }
        }

    if (MODE == 0 && seg >= 1) {
        __syncthreads();
        int b = m0 >> 11;
        int l0 = m0 & 2047;
        u16* dst = outT + ((seg == 2) ? 2097152 : 0)
                 + (long)b * 524288 + (long)tid * 2048 + l0;
        const u16* src = T + tid * 65;
#pragma unroll
        for (int i = 0; i < 8; ++i) {
            u16 tmp[8];
#pragma unroll
            for (int k2 = 0; k2 < 8; ++k2) tmp[k2] = src[i * 8 + k2];
            *(uint4*)(dst + i * 8) = *(uint4*)tmp;
        }
    }
}

// ---------------------------------------------------------------------------
// Fused long-range attention (verified round 2)
// ---------------------------------------------------------------------------
__global__ __launch_bounds__(256) void attn_k(
    const u16* __restrict__ qb, const u16* __restrict__ kcb,
    const u16* __restrict__ vcT, u16* __restrict__ lngb)
{
    __shared__ u16 Ps[64 * 128];

    int bh = blockIdx.y;
    int b = bh >> 2, h = bh & 3;
    int l0 = blockIdx.x * 64;
    int tid = threadIdx.x, wave = tid >> 6, lane = tid & 63;
    int c = lane & 15, g = lane >> 4;

    const u16* kc = kcb + (long)b * (RR * DV) + h * 64;
    const u16* qg = qb + ((long)(b * LSEQ + l0)) * DV + h * 64;
    const u16* vg = vcT + ((long)b * DV + h * 64) * RR;

    f32x4 acc[8];
#pragma unroll
    for (int mi = 0; mi < 8; ++mi) acc[mi] = (f32x4){0.f, 0.f, 0.f, 0.f};

#pragma unroll
    for (int kh = 0; kh < 2; ++kh) {
        bf16x8 bq = *(const bf16x8*)(qg + (long)(wave * 16 + c) * DV + kh * 32 + g * 8);
#pragma unroll
        for (int mi = 0; mi < 8; ++mi) {
            bf16x8 af = *(const bf16x8*)(kc + (long)(mi * 16 + c) * DV + kh * 32 + g * 8);
            acc[mi] = __builtin_amdgcn_mfma_f32_16x16x32_bf16(af, bq, acc[mi], 0, 0, 0);
        }
    }

    float mx = -INFINITY;
#pragma unroll
    for (int mi = 0; mi < 8; ++mi)
#pragma unroll
        for (int j = 0; j < 4; ++j) {
            acc[mi][j] *= 0.125f;
            mx = fmaxf(mx, acc[mi][j]);
        }
    mx = fmaxf(mx, __shfl_xor(mx, 16));
    mx = fmaxf(mx, __shfl_xor(mx, 32));
    float den = 0.f;
#pragma unroll
    for (int mi = 0; mi < 8; ++mi)
#pragma unroll
        for (int j = 0; j < 4; ++j) {
            acc[mi][j] = __expf(acc[mi][j] - mx);
            den += acc[mi][j];
        }
    den += __shfl_xor(den, 16);
    den += __shfl_xor(den, 32);
    float inv = 1.0f / den;

    int l = wave * 16 + c;
#pragma unroll
    for (int mi = 0; mi < 8; ++mi) {
        short4 sv;
        sv.x = (short)f2bf(acc[mi][0] * inv);
        sv.y = (short)f2bf(acc[mi][1] * inv);
        sv.z = (short)f2bf(acc[mi][2] * inv);
        sv.w = (short)f2bf(acc[mi][3] * inv);
        int byte = l * 256 + ((mi * 32 + g * 8) ^ ((l & 7) << 4));
        *(short4*)((char*)Ps + byte) = sv;
    }
    __syncthreads();

    f32x4 a2[4];
#pragma unroll
    for (int ni = 0; ni < 4; ++ni) a2[ni] = (f32x4){0.f, 0.f, 0.f, 0.f};
#pragma unroll
    for (int kb = 0; kb < 4; ++kb) {
        int kby = kb * 64 + (g << 4);
        bf16x8 pa = *(const bf16x8*)((char*)Ps + l * 256 + (kby ^ ((l & 7) << 4)));
#pragma unroll
        for (int ni = 0; ni < 4; ++ni) {
            bf16x8 vf = *(const bf16x8*)(vg + (long)(ni * 16 + c) * RR + kb * 32 + g * 8);
            a2[ni] = __builtin_amdgcn_mfma_f32_16x16x32_bf16(pa, vf, a2[ni], 0, 0, 0);
        }
    }
#pragma unroll
    for (int ni = 0; ni < 4; ++ni)
#pragma unroll
        for (int j = 0; j < 4; ++j) {
            int lr = wave * 16 + g * 4 + j;
            int dh = ni * 16 + c;
            lngb[((long)(b * LSEQ + l0 + lr)) * DV + h * 64 + dh] = f2bf(a2[ni][j]);
        }
}

// ---------------------------------------------------------------------------
// Preprocessing: weight transposes + s cast + bias concat + icnt zero
// ---------------------------------------------------------------------------
struct WTD { const float* src; u16* dst; int K, N, toff; };
struct WTA { WTD d[9]; };

__global__ __launch_bounds__(256) void prep_k(WTA a,
    const float* __restrict__ sin, u16* __restrict__ sout,
    const float* qb_, const float* kb_, const float* vb_,
    float* qkvb, int* icnt)
{
    int bid = blockIdx.x;
    if (bid < 1312) {
        int di = 0;
#pragma unroll
        for (int i = 1; i < 9; ++i) if (bid >= a.d[i].toff) di = i;
        const float* src = a.d[di].src;
        u16* dst = a.d[di].dst;
        int K = a.d[di].K, N = a.d[di].N;
        int tix = bid - a.d[di].toff;
        int nx = N >> 5;
        int tn = tix % nx, tk = tix / nx;
        int n0 = tn * 32, k0 = tk * 32;

        __shared__ float t[32][33];
        int tx = threadIdx.x & 31, ty = threadIdx.x >> 5;
#pragma unroll
        for (int i = 0; i < 32; i += 8)
            t[ty + i][tx] = src[(long)(k0 + ty + i) * N + n0 + tx];
        __syncthreads();
#pragma unroll
        for (int i = 0; i < 32; i += 8)
            dst[(long)(n0 + ty + i) * K + k0 + tx] = f2bf(t[tx][ty + i]);
    } else if (bid < 3360) {
        int i = ((bid - 1312) * 256 + threadIdx.x) * 4;
        float4 v = *(const float4*)(sin + i);
        sout[i]     = f2bf(v.x);
        sout[i + 1] = f2bf(v.y);
        sout[i + 2] = f2bf(v.z);
        sout[i + 3] = f2bf(v.w);
    } else if (bid == 3360) {
        int i = threadIdx.x;
#pragma unroll
        for (int rep = 0; rep < 3; ++rep) {
            int j = i + rep * 256;
            qkvb[j] = (j < 256) ? qb_[j] : ((j < 512) ? kb_[j - 256] : vb_[j - 512]);
        }
    } else {
        int t = (bid - 3361) * 256 + threadIdx.x;
        if (t < 512) ((int4*)icnt)[t] = (int4){0, 0, 0, 0};
    }
}

// ---------------------------------------------------------------------------
// GAT attention logits: wave-per-row, shfl reduce
// ---------------------------------------------------------------------------
__global__ __launch_bounds__(256) void gat_att_k(
    const u16* __restrict__ h, const float* __restrict__ att_src,
    const float* __restrict__ att_dst, float* __restrict__ a_src,
    float* __restrict__ a_dst)
{
    int row  = blockIdx.x * 4 + (threadIdx.x >> 6);
    int lane = threadIdx.x & 63;
    int c0   = lane * 16;
    int head = lane >> 4;

    float as[16], ad[16];
#pragma unroll
    for (int i = 0; i < 16; ++i) { as[i] = att_src[c0 + i]; ad[i] = att_dst[c0 + i]; }

    const u16* hr = h + (long)row * (HH * DV) + c0;
    bf16x8 v0 = *(const bf16x8*)(hr);
    bf16x8 v1 = *(const bf16x8*)(hr + 8);
    float ps = 0.f, pd = 0.f;
#pragma unroll
    for (int i = 0; i < 8; ++i) {
        float f0 = bf2f((u16)v0[i]), f1 = bf2f((u16)v1[i]);
        ps += f0 * as[i] + f1 * as[i + 8];
        pd += f0 * ad[i] + f1 * ad[i + 8];
    }
#pragma unroll
    for (int m = 1; m <= 8; m <<= 1) {
        ps += __shfl_xor(ps, m);
        pd += __shfl_xor(pd, m);
    }
    if ((lane & 15) == 0) {
        a_src[(long)row * HH + head] = ps;
        a_dst[(long)row * HH + head] = pd;
    }
}

// ---------------------------------------------------------------------------
// CSR build over dst (batch-shared), wide 3-kernel pipeline
// ---------------------------------------------------------------------------
__global__ void csr_count_k(const int* __restrict__ ei, int* __restrict__ cnt)
{
    int i = blockIdx.x * blockDim.x + threadIdx.x;
    if (i >= ETOT) return;
    int dst = (i < EE) ? ei[EE + i] : (i - EE);
    atomicAdd(&cnt[dst], 1);
}

__global__ __launch_bounds__(256) void csr_scan_k(const int* __restrict__ cnt, int* __restrict__ off)
{
    __shared__ int chunk[256];
    int tid = threadIdx.x;
    int base = tid * 8;
    int loc[8];
    int s = 0;
#pragma unroll
    for (int i = 0; i < 8; ++i) { loc[i] = s; s += cnt[base + i]; }
    chunk[tid] = s;
    __syncthreads();
    for (int st = 1; st < 256; st <<= 1) {
        int v = (tid >= st) ? chunk[tid - st] : 0;
        __syncthreads();
        chunk[tid] += v;
        __syncthreads();
    }
    int pre = (tid == 0) ? 0 : chunk[tid - 1];
#pragma unroll
    for (int i = 0; i < 8; ++i) off[base + i] = pre + loc[i];
    if (tid == 255) off[LSEQ] = chunk[255];
}

__global__ void csr_fill_k(const int* __restrict__ ei, const int* __restrict__ off,
                           int* __restrict__ cnt, int* __restrict__ bucket)
{
    int i = blockIdx.x * blockDim.x + threadIdx.x;
    if (i >= ETOT) return;
    int dst = (i < EE) ? ei[EE + i] : (i - EE);
    int p = atomicSub(&cnt[dst], 1) - 1;
    bucket[off[dst] + p] = i;
}

// ---------------------------------------------------------------------------
// GAT scatter-softmax + aggregate: ONE WAVE PER (b,n), single edge pass.
// XCD-locality swizzle: batch b -> XCD pair {2b,2b+1}.
// ---------------------------------------------------------------------------
__global__ __launch_bounds__(256) void gat_gather_k(
    const u16* __restrict__ h, const int* __restrict__ ei,
    const int* __restrict__ off, const int* __restrict__ bucket,
    const float* __restrict__ a_src, const float* __restrict__ a_dst,
    const float* __restrict__ gat_b, u16* __restrict__ out)
{
    int wv = threadIdx.x >> 6, lane = threadIdx.x & 63;
    int id = blockIdx.x;               // 0..2047
    int jg = id >> 3, r8 = id & 7;
    int b  = r8 >> 1;
    int n  = (jg * 2 + (r8 & 1)) * 4 + wv;
    int beg = off[n], deg = off[n + 1] - beg;

    __shared__ int   src_sh[4][64];
    __shared__ float ex_sh[4][64][4];

    const float* asrc_b = a_src + (long)b * LSEQ * HH;
    const float4 ad4 = *(const float4*)(a_dst + ((long)b * LSEQ + n) * HH);
    float adst[4] = { ad4.x, ad4.y, ad4.z, ad4.w };

    int hd = lane >> 4;
    const u16* hb = h + (long)b * LSEQ * (HH * DV) + lane * 16;
    float acc[16];
#pragma unroll
    for (int i = 0; i < 16; ++i) acc[i] = 0.f;
    float sm[4] = { 0.f, 0.f, 0.f, 0.f };

    for (int c0 = 0; c0 < deg; c0 += 64) {
        int idx = c0 + lane;
        if (idx < deg) {
            int eid = bucket[beg + idx];
            int src = (eid < EE) ? ei[eid] : (eid - EE);
            src_sh[wv][lane] = src;
            float4 as4 = *(const float4*)(asrc_b + (long)src * HH);
            float as[4] = { as4.x, as4.y, as4.z, as4.w };
#pragma unroll
            for (int hh = 0; hh < 4; ++hh) {
                float e = as[hh] + adst[hh];
                e = (e >= 0.f) ? e : 0.2f * e;
                float ex = __expf(e);
                ex_sh[wv][lane][hh] = ex;
                sm[hh] += ex;
            }
        }
        int cn = deg - c0; if (cn > 64) cn = 64;
#pragma unroll 2
        for (int j = 0; j < cn; ++j) {
            int src = src_sh[wv][j];
            float al = ex_sh[wv][j][hd];
            const u16* p = hb + (long)src * (HH * DV);
            bf16x8 v0 = *(const bf16x8*)p;
            bf16x8 v1 = *(const bf16x8*)(p + 8);
#pragma unroll
            for (int i = 0; i < 8; ++i) {
                acc[i]     += al * bf2f((u16)v0[i]);
                acc[i + 8] += al * bf2f((u16)v1[i]);
            }
        }
    }

#pragma unroll
    for (int hh = 0; hh < 4; ++hh)
#pragma unroll
        for (int m = 32; m >= 1; m >>= 1)
            sm[hh] += __shfl_xor(sm[hh], m);
    float inv = 1.0f / sm[hd];

    u16 o16[16];
    const float* gb = gat_b + lane * 16;
#pragma unroll
    for (int i = 0; i < 16; ++i) o16[i] = f2bf(acc[i] * inv + gb[i]);
    uint4* op = (uint4*)(out + ((long)b * LSEQ + n) * (HH * DV) + lane * 16);
    op[0] = ((uint4*)o16)[0];
    op[1] = ((uint4*)o16)[1];
}

// pm softmax over L: single global read pass
__global__ __launch_bounds__(256) void colsoftmax_k(const float* __restrict__ pm,
                                                    u16* __restrict__ pmT)
{
    int r = blockIdx.x;
    int b = blockIdx.y;
    int tid = threadIdx.x, wave = tid >> 6, lane = tid & 63;
    const float* base = pm + (long)b * LSEQ * RR + r;
    u16* obase = pmT + ((long)b * RR + r) * LSEQ;

    float x[8];
#pragma unroll
    for (int i = 0; i < 8; ++i) x[i] = base[(long)(tid + i * 256) * RR];

    __shared__ float red[4];
    __shared__ float m_sh, d_sh;
    float mx = x[0];
#pragma unroll
    for (int i = 1; i < 8; ++i) mx = fmaxf(mx, x[i]);
#pragma unroll
    for (int m = 32; m >= 1; m >>= 1) mx = fmaxf(mx, __shfl_xor(mx, m));
    if (lane == 0) red[wave] = mx;
    __syncthreads();
    if (tid == 0) m_sh = fmaxf(fmaxf(red[0], red[1]), fmaxf(red[2], red[3]));
    __syncthreads();
    float m = m_sh;
    float sm = 0.f;
#pragma unroll
    for (int i = 0; i < 8; ++i) { x[i] = __expf(x[i] - m); sm += x[i]; }
#pragma unroll
    for (int mm = 32; mm >= 1; mm >>= 1) sm += __shfl_xor(sm, mm);
    if (lane == 0) red[wave] = sm;
    __syncthreads();
    if (tid == 0) d_sh = red[0] + red[1] + red[2] + red[3];
    __syncthreads();
    float inv = 1.0f / d_sh;
#pragma unroll
    for (int i = 0; i < 8; ++i) obase[tid + i * 256] = f2bf(x[i] * inv);
}

// sum 16 split-K partials -> bf16 kvcb, and (pair==1) transposed vcT
__global__ __launch_bounds__(256) void reduce_kvc_k(
    const float* __restrict__ part, u16* __restrict__ kvcb, u16* __restrict__ vcT)
{
    int pb = blockIdx.z;
    int pair = pb >> 2, b = pb & 3;
    int r0 = blockIdx.y * 32, d0 = blockIdx.x * 64;
    int tid = threadIdx.x;
    __shared__ float t[32][65];
    const float* pp = part + (long)pb * (16 * 32768);
    int r = tid >> 6;
    int d = tid & 63;
#pragma unroll
    for (int i = 0; i < 8; ++i) {
        int rr = r0 + r + i * 4;
        float s = 0.f;
#pragma unroll
        for (int sp = 0; sp < 16; ++sp)
            s += pp[(long)sp * 32768 + rr * 256 + d0 + d];
        kvcb[(long)pb * 32768 + rr * 256 + d0 + d] = f2bf(s);
        t[r + i * 4][d] = s;
    }
    if (pair == 0) return;
    __syncthreads();
    int dd = tid >> 2, rb = (tid & 3) * 8;
    u16 o8[8];
#pragma unroll
    for (int k = 0; k < 8; ++k) o8[k] = f2bf(t[rb + k][dd]);
    *(uint4*)(vcT + ((long)(b * 256 + d0 + dd)) * 128 + r0 + rb) = *(uint4*)o8;
}

// ---------------------------------------------------------------------------
extern "C" void kernel_launch(void* const* d_in, const int* in_sizes, int n_in,
                              void* d_out, int out_size, void* d_ws, size_t ws_size,
                              hipStream_t stream)
{
    const float* s        = (const float*)d_in[0];
    const float* gat_W    = (const float*)d_in[1];
    const float* att_src  = (const float*)d_in[2];
    const float* att_dst  = (const float*)d_in[3];
    const float* gat_b    = (const float*)d_in[4];
    const float* short_W  = (const float*)d_in[5];
    const float* short_b  = (const float*)d_in[6];
    const float* q_W      = (const float*)d_in[7];
    const float* q_b      = (const float*)d_in[8];
    const float* k_W      = (const float*)d_in[9];
    const float* k_b      = (const float*)d_in[10];
    const float* v_W      = (const float*)d_in[11];
    const float* v_b      = (const float*)d_in[12];
    const float* o_W      = (const float*)d_in[13];
    const float* o_b      = (const float*)d_in[14];
    const float* p_W      = (const float*)d_in[15];
    const float* p_b      = (const float*)d_in[16];
    const float* lnq_g    = (const float*)d_in[17];
    const float* lnq_b    = (const float*)d_in[18];
    const float* lnk_g    = (const float*)d_in[19];
    const float* lnk_b    = (const float*)d_in[20];
    const float* lnv_g    = (const float*)d_in[21];
    const float* lnv_b    = (const float*)d_in[22];
    const float* ln1_g    = (const float*)d_in[23];
    const float* ln1_b    = (const float*)d_in[24];
    const float* ln2_g    = (const float*)d_in[25];
    const float* ln2_b    = (const float*)d_in[26];
    const float* f1_W     = (const float*)d_in[27];
    const float* f1_b     = (const float*)d_in[28];
    const float* f2_W     = (const float*)d_in[29];
    const float* f2_b     = (const float*)d_in[30];
    const int*   ei       = (const int*)d_in[31];
    float* out = (float*)d_out;

    const size_t MB = 1024 * 1024;
    char* W = (char*)d_ws;
    u16*   sb      = (u16*)(W);                         // 4MB
    u16*   gatT    = (u16*)(W + 4*MB);                  // 512KB
    u16*   shortT  = (u16*)(W + 4*MB + 524288);         // 512KB
    u16*   qkvT    = (u16*)(W + 4*MB + 1048576);        // 384KB
    u16*   oT      = (u16*)(W + 4*MB + 1441792);        // 128KB
    u16*   pT      = (u16*)(W + 4*MB + 1572864);        // 64KB
    u16*   f1T     = (u16*)(W + 4*MB + 1638400);        // 512KB
    u16*   f2T     = (u16*)(W + 4*MB + 2162688);        // 512KB
    float* qkvb    = (float*)(W + 4*MB + 2686976);      // 3KB
    int*   ioff    = (int*)(W + 4*MB + 2690048);        // 2049
    int*   icnt    = (int*)(W + 4*MB + 2699264);        // 2048
    int*   ibucket = (int*)(W + 4*MB + 2707456);        // 34816
    u16*   h       = (u16*)(W + 8*MB);                  // 16MB
    u16*   ffh     = (u16*)(W + 8*MB);                  // alias h (16MB)
    u16*   gat_out = (u16*)(W + 24*MB);                 // 16MB
    u16*   h1b     = (u16*)(W + 40*MB);                 // 4MB
    u16*   shortb16= (u16*)(W + 44*MB);                 // 4MB
    float* pmraw   = (float*)(W + 48*MB);               // 4MB (dead after colsoftmax)
    float* part    = (float*)(W + 48*MB);               // alias 16MB (dead after reduce_kvc)
    u16*   lngb    = (u16*)(W + 48*MB);                 // alias 4MB (after part dead)
    u16*   qb      = (u16*)(W + 72*MB);                 // 4MB
    u16*   kb      = (u16*)(W + 76*MB);                 // 4MB
    u16*   kvT     = (u16*)(W + 84*MB);                 // 8MB [2 pair][4 b][256][2048]
    u16*   pmT     = (u16*)(W + 92*MB);                 // 2MB
    u16*   kvcb    = (u16*)(W + 94*MB);                 // 512KB
    u16*   vcT     = (u16*)(W + 94*MB + 524288);        // 256KB
    float* a_src   = (float*)(W + 95*MB);               // 128KB
    float* a_dst   = (float*)(W + 95*MB + 131072);      // 128KB

    const int ML = BB * LSEQ;  // 8192

    // ---- prep: weights -> bf16^T, s cast, bias concat, icnt zero ----
    WTA wa;
    wa.d[0] = { gat_W,   gatT,            256, 1024, 0    };
    wa.d[1] = { short_W, shortT,         1024,  256, 256  };
    wa.d[2] = { q_W,     qkvT,            256,  256, 512  };
    wa.d[3] = { k_W,     qkvT + 65536,    256,  256, 576  };
    wa.d[4] = { v_W,     qkvT + 131072,   256,  256, 640  };
    wa.d[5] = { o_W,     oT,              256,  256, 704  };
    wa.d[6] = { p_W,     pT,              256,  128, 768  };
    wa.d[7] = { f1_W,    f1T,             256, 1024, 800  };
    wa.d[8] = { f2_W,    f2T,            1024,  256, 1056 };
    prep_k<<<3363, 256, 0, stream>>>(wa, s, sb, q_b, k_b, v_b, qkvb, icnt);

    // ---- CSR (wide 3-kernel) ----
    csr_count_k<<<(ETOT + 255) / 256, 256, 0, stream>>>(ei, icnt);
    csr_scan_k<<<1, 256, 0, stream>>>(icnt, ioff);
    csr_fill_k<<<(ETOT + 255) / 256, 256, 0, stream>>>(ei, ioff, icnt, ibucket);

    // ---- GAT ----
    mfma_gemm_k<128, 128, 1, 0><<<dim3(8, 64, 1), 256, 0, stream>>>(
        sb, gatT, nullptr, h, ML, 1024, 256, 256, 256, 1024,
        0, 0, 0, 0, 0, 0, 1, 0, 0, 0, 0, 1.f);
    gat_att_k<<<ML / 4, 256, 0, stream>>>(h, att_src, att_dst, a_src, a_dst);
    gat_gather_k<<<2048, 256, 0, stream>>>(h, ei, ioff, ibucket,
                                           a_src, a_dst, gat_b, gat_out);
    mfma_gemm_k<64, 128, 1, 0><<<dim3(2, 128, 1), 256, 0, stream>>>(
        gat_out, shortT, short_b, shortb16, ML, 256, 1024, 1024, 1024, 256,
        0, 0, 0, 0, 0, 0, 1, 0, 0, 0, 0, 1.f);

    // ---- qkv projection + fused LN(q/k/v) + k^T/v^T transposes ----
    gemm_ln_k<0, 64><<<dim3(3, 128), 256, 0, stream>>>(
        sb, qkvT, qkvb, 256, 256,
        lnq_g, lnq_b, lnk_g, lnk_b, lnv_g, lnv_b,
        nullptr, nullptr, qb, kb, kvT, nullptr);

    // pm = softmax_L(k @ p_W + p_b) -> pmT bf16 [b][r][l]
    mfma_gemm_k<64, 64, 0, 0><<<dim3(2, 128, 1), 256, 0, stream>>>(
        kb, pT, p_b, pmraw, ML, 128, 256, 256, 256, 128,
        0, 0, 0, 0, 0, 0, 1, 0, 0, 0, 0, 1.f);
    colsoftmax_k<<<dim3(RR, BB), 256, 0, stream>>>(pmraw, pmT);

    // k_c/v_c via split-K (16 splits): part [pair][b][16][128][256]
    mfma_gemm_k<128, 128, 0, 0><<<dim3(2, 2, 64), 256, 0, stream>>>(
        pmT, kvT, nullptr, part, 128, 256, 2048, 2048, 2048, 256,
        262144, 0, 524288, 0, 524288, 32768, 16, 2097152, 2097152, 128, 1, 1.f);
    reduce_kvc_k<<<dim3(4, 4, 8), 256, 0, stream>>>(part, kvcb, vcT);

    // ---- fused attention ----
    attn_k<<<dim3(LSEQ / 64, BB * HH), 256, 0, stream>>>(qb, kvcb, vcT, lngb);

    // ---- o-proj + fused LN(sb + short + lng) -> h1b ----
    gemm_ln_k<1, 32><<<dim3(1, 256), 256, 0, stream>>>(
        lngb, oT, o_b, 256, 256,
        ln1_g, ln1_b, nullptr, nullptr, nullptr, nullptr,
        sb, shortb16, h1b, nullptr, nullptr, nullptr);

    // FFN
    mfma_gemm_k<128, 128, 1, 1><<<dim3(8, 64, 1), 256, 0, stream>>>(
        h1b, f1T, f1_b, ffh, ML, 1024, 256, 256, 256, 1024,
        0, 0, 0, 0, 0, 0, 1, 0, 0, 0, 0, 1.f);

    // ---- f2 + fused LN(h1 + ff2) -> out (fp32) ----
    gemm_ln_k<2, 32><<<dim3(1, 256), 256, 0, stream>>>(
        ffh, f2T, f2_b, 1024, 1024,
        ln2_g, ln2_b, nullptr, nullptr, nullptr, nullptr,
        h1b, nullptr, nullptr, nullptr, nullptr, out);
}

// Round 17
// 191.992 us; speedup vs baseline: 1.0849x; 1.0201x over previous
//
#include <hip/hip_runtime.h>
#include <math.h>

#define BB   4
#define LSEQ 2048
#define DV   256
#define HH   4
#define RR   128
#define EE   32768
#define ETOT (EE + LSEQ)
#define FFD  1024

typedef unsigned short u16;
typedef __attribute__((ext_vector_type(8))) short bf16x8;
typedef __attribute__((ext_vector_type(4))) float f32x4;

__device__ __forceinline__ u16 f2bf(float f) {
    union { float f; unsigned u; } x; x.f = f;
    unsigned r = x.u + 0x7fff + ((x.u >> 16) & 1);
    return (u16)(r >> 16);
}
__device__ __forceinline__ float bf2f(u16 u) {
    union { unsigned u; float f; } x; x.u = ((unsigned)u) << 16;
    return x.f;
}

__device__ __forceinline__ void gload16(const void* g, void* l) {
    __builtin_amdgcn_global_load_lds(
        (const __attribute__((address_space(1))) unsigned int*)g,
        (__attribute__((address_space(3))) unsigned int*)l, 16, 0, 0);
}

// ---------------------------------------------------------------------------
// bf16 MFMA GEMM. BM in {128,64}, BN in {128,64}, BK=64. (verified)
// ---------------------------------------------------------------------------
template<int BM, int BN, int OUTBF16, int ACT>
__global__ __launch_bounds__(256) void mfma_gemm_k(
    const u16* __restrict__ A, const u16* __restrict__ BT,
    const float* __restrict__ bias, void* __restrict__ Cv,
    int M, int N, int K, int lda, int ldb, int ldc,
    long bsA1, long bsA2, long bsB1, long bsB2, long bsC1, long bsC2,
    int subH, long pairB, long pairC, int ksl, int split, float alpha)
{
    constexpr int BK = 64;
    __shared__ u16 As[BM * BK];
    __shared__ u16 Bs[BN * BK];

    int z = blockIdx.z;
    int zb = z / subH, zh = z - zb * subH;
    int mtiles = M / BM;
    int pair = blockIdx.y / mtiles;
    int mt   = blockIdx.y - pair * mtiles;

    const u16* Ab = A  + zb * bsA1 + zh * bsA2;
    const u16* Bb = BT + zb * bsB1 + zh * bsB2 + (long)pair * pairB;
    int kstart = split ? zh * ksl : 0;
    int kcount = split ? ksl : K;
    int m0 = mt * BM, n0 = blockIdx.x * BN;

    int tid  = threadIdx.x;
    int wave = tid >> 6, lane = tid & 63;
    constexpr int WGN = (BN == 128) ? 2 : 1;
    constexpr int WGM = 4 / WGN;
    constexpr int MI  = BM / (WGM * 16);
    constexpr int NI  = BN / (WGN * 16);
    int wm = wave / WGN, wn = wave - wm * WGN;
    int wmo = wm * (MI * 16);
    int wno = wn * (NI * 16);

    f32x4 acc[MI][NI];
#pragma unroll
    for (int mi = 0; mi < MI; ++mi)
#pragma unroll
        for (int ni = 0; ni < NI; ++ni)
            acc[mi][ni] = (f32x4){0.f, 0.f, 0.f, 0.f};

    constexpr int AIT = (BM * BK / 8) / 256;
    constexpr int BIT = (BN * BK / 8) / 256;

    for (int k0 = 0; k0 < kcount; k0 += BK) {
        int kb = kstart + k0;
#pragma unroll
        for (int i = 0; i < AIT; ++i) {
            int p   = i * 256 + tid;
            int row = p >> 3;
            int kc  = (p & 7) ^ (row & 7);
            const u16* gp = Ab + (long)(m0 + row) * lda + kb + kc * 8;
            gload16(gp, (char*)As + (size_t)(i * 256 + wave * 64) * 16);
        }
#pragma unroll
        for (int i = 0; i < BIT; ++i) {
            int p   = i * 256 + tid;
            int row = p >> 3;
            int kc  = (p & 7) ^ (row & 7);
            const u16* gp = Bb + (long)(n0 + row) * ldb + kb + kc * 8;
            gload16(gp, (char*)Bs + (size_t)(i * 256 + wave * 64) * 16);
        }
        asm volatile("s_waitcnt vmcnt(0)");
        __syncthreads();

        const char* Ac = (const char*)As;
        const char* Bc = (const char*)Bs;
#pragma unroll
        for (int kh = 0; kh < 2; ++kh) {
            bf16x8 af[MI], bfr[NI];
            int kby = kh * 64 + ((lane >> 4) << 4);
#pragma unroll
            for (int mi = 0; mi < MI; ++mi) {
                int r = wmo + mi * 16 + (lane & 15);
                af[mi] = *(const bf16x8*)(Ac + r * 128 + (kby ^ ((r & 7) << 4)));
            }
#pragma unroll
            for (int ni = 0; ni < NI; ++ni) {
                int r = wno + ni * 16 + (lane & 15);
                bfr[ni] = *(const bf16x8*)(Bc + r * 128 + (kby ^ ((r & 7) << 4)));
            }
#pragma unroll
            for (int mi = 0; mi < MI; ++mi)
#pragma unroll
                for (int ni = 0; ni < NI; ++ni)
                    acc[mi][ni] = __builtin_amdgcn_mfma_f32_16x16x32_bf16(
                        af[mi], bfr[ni], acc[mi][ni], 0, 0, 0);
        }
        __syncthreads();
    }

    long cb = zb * bsC1 + zh * bsC2 + (long)pair * pairC;
#pragma unroll
    for (int mi = 0; mi < MI; ++mi) {
#pragma unroll
        for (int ni = 0; ni < NI; ++ni) {
            int col = n0 + wno + ni * 16 + (lane & 15);
            float bv = bias ? bias[col] : 0.f;
#pragma unroll
            for (int j = 0; j < 4; ++j) {
                int row = m0 + wmo + mi * 16 + ((lane >> 4) << 2) + j;
                float v = acc[mi][ni][j] * alpha + bv;
                if (ACT) v = fmaxf(v, 0.f);
                long idx = (long)row * ldc + col + cb;
                if (OUTBF16) ((u16*)Cv)[idx] = f2bf(v);
                else         ((float*)Cv)[idx] = v;
            }
        }
    }
}

// ---------------------------------------------------------------------------
// GEMM (BM templated, BN=256) with fused LayerNorm epilogue.
// MODE 0 (BM=64): qkv proj; seg selects q/k/v; seg0->qb, seg1->kb+kT, seg2->vT.
// MODE 1 (BM=32): o-proj + LN(sb + short + oout) -> outRM (h1b)
// MODE 2 (BM=32): f2 + LN(h1b + f2out) -> outF (fp32 final)
// ---------------------------------------------------------------------------
template<int MODE, int BM>
__global__ __launch_bounds__(256) void gemm_ln_k(
    const u16* __restrict__ A, const u16* __restrict__ BT,
    const float* __restrict__ bias, int K, int lda,
    const float* __restrict__ lg0, const float* __restrict__ lb0,
    const float* __restrict__ lg1, const float* __restrict__ lb1,
    const float* __restrict__ lg2, const float* __restrict__ lb2,
    const u16* __restrict__ resB0, const u16* __restrict__ resB1,
    u16* __restrict__ outRM, u16* __restrict__ outRM2,
    u16* __restrict__ outT, float* __restrict__ outF)
{
    constexpr int BK = 64;
    constexpr int MI = BM / 16;
    constexpr int ABYTES = BM * 128;
    __shared__ char smem[ABYTES + 32768];
    __shared__ float redS[BM][4], redQ[BM][4];
    u16* Asm = (u16*)smem;
    u16* Bsm = (u16*)(smem + ABYTES);

    int seg = blockIdx.x;
    int m0 = blockIdx.y * BM;
    int n0 = seg * 256;
    int tid = threadIdx.x, wave = tid >> 6, lane = tid & 63;
    int c = lane & 15, g = lane >> 4;

    f32x4 acc[MI][4];
#pragma unroll
    for (int mi = 0; mi < MI; ++mi)
#pragma unroll
        for (int ni = 0; ni < 4; ++ni)
            acc[mi][ni] = (f32x4){0.f, 0.f, 0.f, 0.f};

    constexpr int AIT = (BM * BK / 8) / 256;

    for (int k0 = 0; k0 < K; k0 += BK) {
#pragma unroll
        for (int i = 0; i < AIT; ++i) {
            int p   = i * 256 + tid;
            int row = p >> 3;
            int kc  = (p & 7) ^ (row & 7);
            gload16(A + (long)(m0 + row) * lda + k0 + kc * 8,
                    smem + (size_t)(i * 256 + wave * 64) * 16);
        }
#pragma unroll
        for (int i = 0; i < 8; ++i) {           // B: 256x64
            int p   = i * 256 + tid;
            int row = p >> 3;
            int kc  = (p & 7) ^ (row & 7);
            gload16(BT + (long)(n0 + row) * K + k0 + kc * 8,
                    smem + ABYTES + (size_t)(i * 256 + wave * 64) * 16);
        }
        asm volatile("s_waitcnt vmcnt(0)");
        __syncthreads();

        const char* Ac = (const char*)Asm;
        const char* Bc = (const char*)Bsm;
#pragma unroll
        for (int kh = 0; kh < 2; ++kh) {
            bf16x8 af[MI], bfr[4];
            int kby = kh * 64 + (g << 4);
#pragma unroll
            for (int mi = 0; mi < MI; ++mi) {
                int r = mi * 16 + c;
                af[mi] = *(const bf16x8*)(Ac + r * 128 + (kby ^ ((r & 7) << 4)));
            }
#pragma unroll
            for (int ni = 0; ni < 4; ++ni) {
                int r = wave * 64 + ni * 16 + c;
                bfr[ni] = *(const bf16x8*)(Bc + r * 128 + (kby ^ ((r & 7) << 4)));
            }
#pragma unroll
            for (int mi = 0; mi < MI; ++mi)
#pragma unroll
                for (int ni = 0; ni < 4; ++ni)
                    acc[mi][ni] = __builtin_amdgcn_mfma_f32_16x16x32_bf16(
                        af[mi], bfr[ni], acc[mi][ni], 0, 0, 0);
        }
        __syncthreads();
    }

    // ---- bias + residuals ----
#pragma unroll
    for (int mi = 0; mi < MI; ++mi)
#pragma unroll
        for (int ni = 0; ni < 4; ++ni) {
            int colL = wave * 64 + ni * 16 + c;
            float bv = bias[n0 + colL];
#pragma unroll
            for (int j = 0; j < 4; ++j) {
                int row = mi * 16 + g * 4 + j;
                float v = acc[mi][ni][j] + bv;
                if (MODE == 1) {
                    long idx = (long)(m0 + row) * 256 + colL;
                    v += bf2f(resB0[idx]) + bf2f(resB1[idx]);
                }
                if (MODE == 2) {
                    long idx = (long)(m0 + row) * 256 + colL;
                    v += bf2f(resB0[idx]);
                }
                acc[mi][ni][j] = v;
            }
        }

    // ---- per-row sum / sumsq ----
#pragma unroll
    for (int mi = 0; mi < MI; ++mi)
#pragma unroll
        for (int j = 0; j < 4; ++j) {
            float s1 = 0.f, q1 = 0.f;
#pragma unroll
            for (int ni = 0; ni < 4; ++ni) {
                float v = acc[mi][ni][j];
                s1 += v; q1 += v * v;
            }
#pragma unroll
            for (int m = 1; m <= 8; m <<= 1) {
                s1 += __shfl_xor(s1, m);
                q1 += __shfl_xor(q1, m);
            }
            if (c == 0) {
                int row = mi * 16 + g * 4 + j;
                redS[row][wave] = s1;
                redQ[row][wave] = q1;
            }
        }
    __syncthreads();

    const float* gam;
    const float* bet;
    if (MODE == 0) {
        gam = (seg == 0) ? lg0 : (seg == 1) ? lg1 : lg2;
        bet = (seg == 0) ? lb0 : (seg == 1) ? lb1 : lb2;
    } else { gam = lg0; bet = lb0; }

    u16* T = (u16*)smem;   // [256][65] bf16 — only MODE 0 (BM=64); reads done

    float gv[4], bv2[4];
#pragma unroll
    for (int ni = 0; ni < 4; ++ni) {
        int colL = wave * 64 + ni * 16 + c;
        gv[ni] = gam[colL];
        bv2[ni] = bet[colL];
    }

#pragma unroll
    for (int mi = 0; mi < MI; ++mi)
#pragma unroll
        for (int j = 0; j < 4; ++j) {
            int row = mi * 16 + g * 4 + j;
            float S = redS[row][0] + redS[row][1] + redS[row][2] + redS[row][3];
            float Q = redQ[row][0] + redQ[row][1] + redQ[row][2] + redQ[row][3];
            float mu = S * (1.0f / 256.f);
            float var = Q * (1.0f / 256.f) - mu * mu;
            float rs = rsqrtf(var + 1e-5f);
#pragma unroll
            for (int ni = 0; ni < 4; ++ni) {
                int colL = wave * 64 + ni * 16 + c;
                float o = (acc[mi][ni][j] - mu) * rs * gv[ni] + bv2[ni];
                long idx = (long)(m0 + row) * 256 + colL;
                if (MODE == 0) {
                    u16 ob = f2bf(o);
                    if (seg == 0)      outRM[idx]  = ob;
                    else if (seg == 1) { outRM2[idx] = ob; T[colL * 65 + row] = ob; }
                    else               T[colL * 65 + row] = ob;
                } else if (MODE == 1) {
                    outRM[idx] = f2bf(o);
                } else {
                    outF[idx] = o;
                }
            }
        }

    if (MODE == 0 && seg >= 1) {
        __syncthreads();
        int b = m0 >> 11;
        int l0 = m0 & 2047;
        u16* dst = outT + ((seg == 2) ? 2097152 : 0)
                 + (long)b * 524288 + (long)tid * 2048 + l0;
        const u16* src = T + tid * 65;
#pragma unroll
        for (int i = 0; i < 8; ++i) {
            u16 tmp[8];
#pragma unroll
            for (int k2 = 0; k2 < 8; ++k2) tmp[k2] = src[i * 8 + k2];
            *(uint4*)(dst + i * 8) = *(uint4*)tmp;
        }
    }
}

// ---------------------------------------------------------------------------
// Fused long-range attention (verified round 2)
// ---------------------------------------------------------------------------
__global__ __launch_bounds__(256) void attn_k(
    const u16* __restrict__ qb, const u16* __restrict__ kcb,
    const u16* __restrict__ vcT, u16* __restrict__ lngb)
{
    __shared__ u16 Ps[64 * 128];

    int bh = blockIdx.y;
    int b = bh >> 2, h = bh & 3;
    int l0 = blockIdx.x * 64;
    int tid = threadIdx.x, wave = tid >> 6, lane = tid & 63;
    int c = lane & 15, g = lane >> 4;

    const u16* kc = kcb + (long)b * (RR * DV) + h * 64;
    const u16* qg = qb + ((long)(b * LSEQ + l0)) * DV + h * 64;
    const u16* vg = vcT + ((long)b * DV + h * 64) * RR;

    f32x4 acc[8];
#pragma unroll
    for (int mi = 0; mi < 8; ++mi) acc[mi] = (f32x4){0.f, 0.f, 0.f, 0.f};

#pragma unroll
    for (int kh = 0; kh < 2; ++kh) {
        bf16x8 bq = *(const bf16x8*)(qg + (long)(wave * 16 + c) * DV + kh * 32 + g * 8);
#pragma unroll
        for (int mi = 0; mi < 8; ++mi) {
            bf16x8 af = *(const bf16x8*)(kc + (long)(mi * 16 + c) * DV + kh * 32 + g * 8);
            acc[mi] = __builtin_amdgcn_mfma_f32_16x16x32_bf16(af, bq, acc[mi], 0, 0, 0);
        }
    }

    float mx = -INFINITY;
#pragma unroll
    for (int mi = 0; mi < 8; ++mi)
#pragma unroll
        for (int j = 0; j < 4; ++j) {
            acc[mi][j] *= 0.125f;
            mx = fmaxf(mx, acc[mi][j]);
        }
    mx = fmaxf(mx, __shfl_xor(mx, 16));
    mx = fmaxf(mx, __shfl_xor(mx, 32));
    float den = 0.f;
#pragma unroll
    for (int mi = 0; mi < 8; ++mi)
#pragma unroll
        for (int j = 0; j < 4; ++j) {
            acc[mi][j] = __expf(acc[mi][j] - mx);
            den += acc[mi][j];
        }
    den += __shfl_xor(den, 16);
    den += __shfl_xor(den, 32);
    float inv = 1.0f / den;

    int l = wave * 16 + c;
#pragma unroll
    for (int mi = 0; mi < 8; ++mi) {
        short4 sv;
        sv.x = (short)f2bf(acc[mi][0] * inv);
        sv.y = (short)f2bf(acc[mi][1] * inv);
        sv.z = (short)f2bf(acc[mi][2] * inv);
        sv.w = (short)f2bf(acc[mi][3] * inv);
        int byte = l * 256 + ((mi * 32 + g * 8) ^ ((l & 7) << 4));
        *(short4*)((char*)Ps + byte) = sv;
    }
    __syncthreads();

    f32x4 a2[4];
#pragma unroll
    for (int ni = 0; ni < 4; ++ni) a2[ni] = (f32x4){0.f, 0.f, 0.f, 0.f};
#pragma unroll
    for (int kb = 0; kb < 4; ++kb) {
        int kby = kb * 64 + (g << 4);
        bf16x8 pa = *(const bf16x8*)((char*)Ps + l * 256 + (kby ^ ((l & 7) << 4)));
#pragma unroll
        for (int ni = 0; ni < 4; ++ni) {
            bf16x8 vf = *(const bf16x8*)(vg + (long)(ni * 16 + c) * RR + kb * 32 + g * 8);
            a2[ni] = __builtin_amdgcn_mfma_f32_16x16x32_bf16(pa, vf, a2[ni], 0, 0, 0);
        }
    }
#pragma unroll
    for (int ni = 0; ni < 4; ++ni)
#pragma unroll
        for (int j = 0; j < 4; ++j) {
            int lr = wave * 16 + g * 4 + j;
            int dh = ni * 16 + c;
            lngb[((long)(b * LSEQ + l0 + lr)) * DV + h * 64 + dh] = f2bf(a2[ni][j]);
        }
}

// ---------------------------------------------------------------------------
// Preprocessing: weight transposes + s cast + bias concat + icnt zero
// ---------------------------------------------------------------------------
struct WTD { const float* src; u16* dst; int K, N, toff; };
struct WTA { WTD d[9]; };

__global__ __launch_bounds__(256) void prep_k(WTA a,
    const float* __restrict__ sin, u16* __restrict__ sout,
    const float* qb_, const float* kb_, const float* vb_,
    float* qkvb, int* icnt)
{
    int bid = blockIdx.x;
    if (bid < 1312) {
        int di = 0;
#pragma unroll
        for (int i = 1; i < 9; ++i) if (bid >= a.d[i].toff) di = i;
        const float* src = a.d[di].src;
        u16* dst = a.d[di].dst;
        int K = a.d[di].K, N = a.d[di].N;
        int tix = bid - a.d[di].toff;
        int nx = N >> 5;
        int tn = tix % nx, tk = tix / nx;
        int n0 = tn * 32, k0 = tk * 32;

        __shared__ float t[32][33];
        int tx = threadIdx.x & 31, ty = threadIdx.x >> 5;
#pragma unroll
        for (int i = 0; i < 32; i += 8)
            t[ty + i][tx] = src[(long)(k0 + ty + i) * N + n0 + tx];
        __syncthreads();
#pragma unroll
        for (int i = 0; i < 32; i += 8)
            dst[(long)(n0 + ty + i) * K + k0 + tx] = f2bf(t[tx][ty + i]);
    } else if (bid < 3360) {
        int i = ((bid - 1312) * 256 + threadIdx.x) * 4;
        float4 v = *(const float4*)(sin + i);
        sout[i]     = f2bf(v.x);
        sout[i + 1] = f2bf(v.y);
        sout[i + 2] = f2bf(v.z);
        sout[i + 3] = f2bf(v.w);
    } else if (bid == 3360) {
        int i = threadIdx.x;
#pragma unroll
        for (int rep = 0; rep < 3; ++rep) {
            int j = i + rep * 256;
            qkvb[j] = (j < 256) ? qb_[j] : ((j < 512) ? kb_[j - 256] : vb_[j - 512]);
        }
    } else {
        int t = (bid - 3361) * 256 + threadIdx.x;
        if (t < 512) ((int4*)icnt)[t] = (int4){0, 0, 0, 0};
    }
}

// ---------------------------------------------------------------------------
// GAT attention logits: wave-per-row, shfl reduce
// ---------------------------------------------------------------------------
__global__ __launch_bounds__(256) void gat_att_k(
    const u16* __restrict__ h, const float* __restrict__ att_src,
    const float* __restrict__ att_dst, float* __restrict__ a_src,
    float* __restrict__ a_dst)
{
    int row  = blockIdx.x * 4 + (threadIdx.x >> 6);
    int lane = threadIdx.x & 63;
    int c0   = lane * 16;
    int head = lane >> 4;

    float as[16], ad[16];
#pragma unroll
    for (int i = 0; i < 16; ++i) { as[i] = att_src[c0 + i]; ad[i] = att_dst[c0 + i]; }

    const u16* hr = h + (long)row * (HH * DV) + c0;
    bf16x8 v0 = *(const bf16x8*)(hr);
    bf16x8 v1 = *(const bf16x8*)(hr + 8);
    float ps = 0.f, pd = 0.f;
#pragma unroll
    for (int i = 0; i < 8; ++i) {
        float f0 = bf2f((u16)v0[i]), f1 = bf2f((u16)v1[i]);
        ps += f0 * as[i] + f1 * as[i + 8];
        pd += f0 * ad[i] + f1 * ad[i + 8];
    }
#pragma unroll
    for (int m = 1; m <= 8; m <<= 1) {
        ps += __shfl_xor(ps, m);
        pd += __shfl_xor(pd, m);
    }
    if ((lane & 15) == 0) {
        a_src[(long)row * HH + head] = ps;
        a_dst[(long)row * HH + head] = pd;
    }
}

// ---------------------------------------------------------------------------
// CSR build over dst (batch-shared), wide 3-kernel pipeline
// ---------------------------------------------------------------------------
__global__ void csr_count_k(const int* __restrict__ ei, int* __restrict__ cnt)
{
    int i = blockIdx.x * blockDim.x + threadIdx.x;
    if (i >= ETOT) return;
    int dst = (i < EE) ? ei[EE + i] : (i - EE);
    atomicAdd(&cnt[dst], 1);
}

__global__ __launch_bounds__(256) void csr_scan_k(const int* __restrict__ cnt, int* __restrict__ off)
{
    __shared__ int chunk[256];
    int tid = threadIdx.x;
    int base = tid * 8;
    int loc[8];
    int s = 0;
#pragma unroll
    for (int i = 0; i < 8; ++i) { loc[i] = s; s += cnt[base + i]; }
    chunk[tid] = s;
    __syncthreads();
    for (int st = 1; st < 256; st <<= 1) {
        int v = (tid >= st) ? chunk[tid - st] : 0;
        __syncthreads();
        chunk[tid] += v;
        __syncthreads();
    }
    int pre = (tid == 0) ? 0 : chunk[tid - 1];
#pragma unroll
    for (int i = 0; i < 8; ++i) off[base + i] = pre + loc[i];
    if (tid == 255) off[LSEQ] = chunk[255];
}

__global__ void csr_fill_k(const int* __restrict__ ei, const int* __restrict__ off,
                           int* __restrict__ cnt, int* __restrict__ bucket)
{
    int i = blockIdx.x * blockDim.x + threadIdx.x;
    if (i >= ETOT) return;
    int dst = (i < EE) ? ei[EE + i] : (i - EE);
    int p = atomicSub(&cnt[dst], 1) - 1;
    bucket[off[dst] + p] = i;
}

// ---------------------------------------------------------------------------
// GAT scatter-softmax + aggregate: ONE WAVE PER (b,n), single edge pass.
// XCD-locality swizzle: batch b -> XCD pair {2b,2b+1}.
// ---------------------------------------------------------------------------
__global__ __launch_bounds__(256) void gat_gather_k(
    const u16* __restrict__ h, const int* __restrict__ ei,
    const int* __restrict__ off, const int* __restrict__ bucket,
    const float* __restrict__ a_src, const float* __restrict__ a_dst,
    const float* __restrict__ gat_b, u16* __restrict__ out)
{
    int wv = threadIdx.x >> 6, lane = threadIdx.x & 63;
    int id = blockIdx.x;               // 0..2047
    int jg = id >> 3, r8 = id & 7;
    int b  = r8 >> 1;
    int n  = (jg * 2 + (r8 & 1)) * 4 + wv;
    int beg = off[n], deg = off[n + 1] - beg;

    __shared__ int   src_sh[4][64];
    __shared__ float ex_sh[4][64][4];

    const float* asrc_b = a_src + (long)b * LSEQ * HH;
    const float4 ad4 = *(const float4*)(a_dst + ((long)b * LSEQ + n) * HH);
    float adst[4] = { ad4.x, ad4.y, ad4.z, ad4.w };

    int hd = lane >> 4;
    const u16* hb = h + (long)b * LSEQ * (HH * DV) + lane * 16;
    float acc[16];
#pragma unroll
    for (int i = 0; i < 16; ++i) acc[i] = 0.f;
    float sm[4] = { 0.f, 0.f, 0.f, 0.f };

    for (int c0 = 0; c0 < deg; c0 += 64) {
        int idx = c0 + lane;
        if (idx < deg) {
            int eid = bucket[beg + idx];
            int src = (eid < EE) ? ei[eid] : (eid - EE);
            src_sh[wv][lane] = src;
            float4 as4 = *(const float4*)(asrc_b + (long)src * HH);
            float as[4] = { as4.x, as4.y, as4.z, as4.w };
#pragma unroll
            for (int hh = 0; hh < 4; ++hh) {
                float e = as[hh] + adst[hh];
                e = (e >= 0.f) ? e : 0.2f * e;
                float ex = __expf(e);
                ex_sh[wv][lane][hh] = ex;
                sm[hh] += ex;
            }
        }
        int cn = deg - c0; if (cn > 64) cn = 64;
#pragma unroll 2
        for (int j = 0; j < cn; ++j) {
            int src = src_sh[wv][j];
            float al = ex_sh[wv][j][hd];
            const u16* p = hb + (long)src * (HH * DV);
            bf16x8 v0 = *(const bf16x8*)p;
            bf16x8 v1 = *(const bf16x8*)(p + 8);
#pragma unroll
            for (int i = 0; i < 8; ++i) {
                acc[i]     += al * bf2f((u16)v0[i]);
                acc[i + 8] += al * bf2f((u16)v1[i]);
            }
        }
    }

#pragma unroll
    for (int hh = 0; hh < 4; ++hh)
#pragma unroll
        for (int m = 32; m >= 1; m >>= 1)
            sm[hh] += __shfl_xor(sm[hh], m);
    float inv = 1.0f / sm[hd];

    u16 o16[16];
    const float* gb = gat_b + lane * 16;
#pragma unroll
    for (int i = 0; i < 16; ++i) o16[i] = f2bf(acc[i] * inv + gb[i]);
    uint4* op = (uint4*)(out + ((long)b * LSEQ + n) * (HH * DV) + lane * 16);
    op[0] = ((uint4*)o16)[0];
    op[1] = ((uint4*)o16)[1];
}

// pm softmax over L: single global read pass (bf16 logits in)
__global__ __launch_bounds__(256) void colsoftmax_k(const u16* __restrict__ pm,
                                                    u16* __restrict__ pmT)
{
    int r = blockIdx.x;
    int b = blockIdx.y;
    int tid = threadIdx.x, wave = tid >> 6, lane = tid & 63;
    const u16* base = pm + (long)b * LSEQ * RR + r;
    u16* obase = pmT + ((long)b * RR + r) * LSEQ;

    float x[8];
#pragma unroll
    for (int i = 0; i < 8; ++i) x[i] = bf2f(base[(long)(tid + i * 256) * RR]);

    __shared__ float red[4];
    __shared__ float m_sh, d_sh;
    float mx = x[0];
#pragma unroll
    for (int i = 1; i < 8; ++i) mx = fmaxf(mx, x[i]);
#pragma unroll
    for (int m = 32; m >= 1; m >>= 1) mx = fmaxf(mx, __shfl_xor(mx, m));
    if (lane == 0) red[wave] = mx;
    __syncthreads();
    if (tid == 0) m_sh = fmaxf(fmaxf(red[0], red[1]), fmaxf(red[2], red[3]));
    __syncthreads();
    float m = m_sh;
    float sm = 0.f;
#pragma unroll
    for (int i = 0; i < 8; ++i) { x[i] = __expf(x[i] - m); sm += x[i]; }
#pragma unroll
    for (int mm = 32; mm >= 1; mm >>= 1) sm += __shfl_xor(sm, mm);
    if (lane == 0) red[wave] = sm;
    __syncthreads();
    if (tid == 0) d_sh = red[0] + red[1] + red[2] + red[3];
    __syncthreads();
    float inv = 1.0f / d_sh;
#pragma unroll
    for (int i = 0; i < 8; ++i) obase[tid + i * 256] = f2bf(x[i] * inv);
}

// sum 8 split-K partials -> bf16 kvcb, and (pair==1) transposed vcT
__global__ __launch_bounds__(256) void reduce_kvc_k(
    const float* __restrict__ part, u16* __restrict__ kvcb, u16* __restrict__ vcT)
{
    int pb = blockIdx.z;
    int pair = pb >> 2, b = pb & 3;
    int r0 = blockIdx.y * 32, d0 = blockIdx.x * 64;
    int tid = threadIdx.x;
    __shared__ float t[32][65];
    const float* pp = part + (long)pb * (8 * 32768);
    int r = tid >> 6;
    int d = tid & 63;
#pragma unroll
    for (int i = 0; i < 8; ++i) {
        int rr = r0 + r + i * 4;
        float s = 0.f;
#pragma unroll
        for (int sp = 0; sp < 8; ++sp)
            s += pp[(long)sp * 32768 + rr * 256 + d0 + d];
        kvcb[(long)pb * 32768 + rr * 256 + d0 + d] = f2bf(s);
        t[r + i * 4][d] = s;
    }
    if (pair == 0) return;
    __syncthreads();
    int dd = tid >> 2, rb = (tid & 3) * 8;
    u16 o8[8];
#pragma unroll
    for (int k = 0; k < 8; ++k) o8[k] = f2bf(t[rb + k][dd]);
    *(uint4*)(vcT + ((long)(b * 256 + d0 + dd)) * 128 + r0 + rb) = *(uint4*)o8;
}

// ---------------------------------------------------------------------------
extern "C" void kernel_launch(void* const* d_in, const int* in_sizes, int n_in,
                              void* d_out, int out_size, void* d_ws, size_t ws_size,
                              hipStream_t stream)
{
    const float* s        = (const float*)d_in[0];
    const float* gat_W    = (const float*)d_in[1];
    const float* att_src  = (const float*)d_in[2];
    const float* att_dst  = (const float*)d_in[3];
    const float* gat_b    = (const float*)d_in[4];
    const float* short_W  = (const float*)d_in[5];
    const float* short_b  = (const float*)d_in[6];
    const float* q_W      = (const float*)d_in[7];
    const float* q_b      = (const float*)d_in[8];
    const float* k_W      = (const float*)d_in[9];
    const float* k_b      = (const float*)d_in[10];
    const float* v_W      = (const float*)d_in[11];
    const float* v_b      = (const float*)d_in[12];
    const float* o_W      = (const float*)d_in[13];
    const float* o_b      = (const float*)d_in[14];
    const float* p_W      = (const float*)d_in[15];
    const float* p_b      = (const float*)d_in[16];
    const float* lnq_g    = (const float*)d_in[17];
    const float* lnq_b    = (const float*)d_in[18];
    const float* lnk_g    = (const float*)d_in[19];
    const float* lnk_b    = (const float*)d_in[20];
    const float* lnv_g    = (const float*)d_in[21];
    const float* lnv_b    = (const float*)d_in[22];
    const float* ln1_g    = (const float*)d_in[23];
    const float* ln1_b    = (const float*)d_in[24];
    const float* ln2_g    = (const float*)d_in[25];
    const float* ln2_b    = (const float*)d_in[26];
    const float* f1_W     = (const float*)d_in[27];
    const float* f1_b     = (const float*)d_in[28];
    const float* f2_W     = (const float*)d_in[29];
    const float* f2_b     = (const float*)d_in[30];
    const int*   ei       = (const int*)d_in[31];
    float* out = (float*)d_out;

    const size_t MB = 1024 * 1024;
    char* W = (char*)d_ws;
    u16*   sb      = (u16*)(W);                         // 4MB
    u16*   gatT    = (u16*)(W + 4*MB);                  // 512KB
    u16*   shortT  = (u16*)(W + 4*MB + 524288);         // 512KB
    u16*   qkvT    = (u16*)(W + 4*MB + 1048576);        // 384KB
    u16*   oT      = (u16*)(W + 4*MB + 1441792);        // 128KB
    u16*   pT      = (u16*)(W + 4*MB + 1572864);        // 64KB
    u16*   f1T     = (u16*)(W + 4*MB + 1638400);        // 512KB
    u16*   f2T     = (u16*)(W + 4*MB + 2162688);        // 512KB
    float* qkvb    = (float*)(W + 4*MB + 2686976);      // 3KB
    int*   ioff    = (int*)(W + 4*MB + 2690048);        // 2049
    int*   icnt    = (int*)(W + 4*MB + 2699264);        // 2048
    int*   ibucket = (int*)(W + 4*MB + 2707456);        // 34816
    u16*   h       = (u16*)(W + 8*MB);                  // 16MB
    u16*   ffh     = (u16*)(W + 8*MB);                  // alias h (16MB)
    u16*   gat_out = (u16*)(W + 24*MB);                 // 16MB
    u16*   h1b     = (u16*)(W + 40*MB);                 // 4MB
    u16*   shortb16= (u16*)(W + 44*MB);                 // 4MB
    u16*   pmraw16 = (u16*)(W + 48*MB);                 // 2MB (dead after colsoftmax)
    float* part    = (float*)(W + 48*MB);               // alias 8MB (dead after reduce_kvc)
    u16*   lngb    = (u16*)(W + 48*MB);                 // alias 4MB (after part dead)
    u16*   qb      = (u16*)(W + 72*MB);                 // 4MB
    u16*   kb      = (u16*)(W + 76*MB);                 // 4MB
    u16*   kvT     = (u16*)(W + 84*MB);                 // 8MB [2 pair][4 b][256][2048]
    u16*   pmT     = (u16*)(W + 92*MB);                 // 2MB
    u16*   kvcb    = (u16*)(W + 94*MB);                 // 512KB
    u16*   vcT     = (u16*)(W + 94*MB + 524288);        // 256KB
    float* a_src   = (float*)(W + 95*MB);               // 128KB
    float* a_dst   = (float*)(W + 95*MB + 131072);      // 128KB

    const int ML = BB * LSEQ;  // 8192

    // ---- prep: weights -> bf16^T, s cast, bias concat, icnt zero ----
    WTA wa;
    wa.d[0] = { gat_W,   gatT,            256, 1024, 0    };
    wa.d[1] = { short_W, shortT,         1024,  256, 256  };
    wa.d[2] = { q_W,     qkvT,            256,  256, 512  };
    wa.d[3] = { k_W,     qkvT + 65536,    256,  256, 576  };
    wa.d[4] = { v_W,     qkvT + 131072,   256,  256, 640  };
    wa.d[5] = { o_W,     oT,              256,  256, 704  };
    wa.d[6] = { p_W,     pT,              256,  128, 768  };
    wa.d[7] = { f1_W,    f1T,             256, 1024, 800  };
    wa.d[8] = { f2_W,    f2T,            1024,  256, 1056 };
    prep_k<<<3363, 256, 0, stream>>>(wa, s, sb, q_b, k_b, v_b, qkvb, icnt);

    // ---- CSR (wide 3-kernel) ----
    csr_count_k<<<(ETOT + 255) / 256, 256, 0, stream>>>(ei, icnt);
    csr_scan_k<<<1, 256, 0, stream>>>(icnt, ioff);
    csr_fill_k<<<(ETOT + 255) / 256, 256, 0, stream>>>(ei, ioff, icnt, ibucket);

    // ---- GAT ----
    mfma_gemm_k<128, 128, 1, 0><<<dim3(8, 64, 1), 256, 0, stream>>>(
        sb, gatT, nullptr, h, ML, 1024, 256, 256, 256, 1024,
        0, 0, 0, 0, 0, 0, 1, 0, 0, 0, 0, 1.f);
    gat_att_k<<<ML / 4, 256, 0, stream>>>(h, att_src, att_dst, a_src, a_dst);
    gat_gather_k<<<2048, 256, 0, stream>>>(h, ei, ioff, ibucket,
                                           a_src, a_dst, gat_b, gat_out);
    mfma_gemm_k<64, 128, 1, 0><<<dim3(2, 128, 1), 256, 0, stream>>>(
        gat_out, shortT, short_b, shortb16, ML, 256, 1024, 1024, 1024, 256,
        0, 0, 0, 0, 0, 0, 1, 0, 0, 0, 0, 1.f);

    // ---- qkv projection + fused LN(q/k/v) + k^T/v^T transposes ----
    gemm_ln_k<0, 64><<<dim3(3, 128), 256, 0, stream>>>(
        sb, qkvT, qkvb, 256, 256,
        lnq_g, lnq_b, lnk_g, lnk_b, lnv_g, lnv_b,
        nullptr, nullptr, qb, kb, kvT, nullptr);

    // pm = softmax_L(k @ p_W + p_b) -> pmT bf16 [b][r][l]  (bf16 logits)
    mfma_gemm_k<64, 64, 1, 0><<<dim3(2, 128, 1), 256, 0, stream>>>(
        kb, pT, p_b, pmraw16, ML, 128, 256, 256, 256, 128,
        0, 0, 0, 0, 0, 0, 1, 0, 0, 0, 0, 1.f);
    colsoftmax_k<<<dim3(RR, BB), 256, 0, stream>>>(pmraw16, pmT);

    // k_c/v_c via split-K (8 splits): part [pair][b][8][128][256]
    mfma_gemm_k<128, 128, 0, 0><<<dim3(2, 2, 32), 256, 0, stream>>>(
        pmT, kvT, nullptr, part, 128, 256, 2048, 2048, 2048, 256,
        262144, 0, 524288, 0, 262144, 32768, 8, 2097152, 1048576, 256, 1, 1.f);
    reduce_kvc_k<<<dim3(4, 4, 8), 256, 0, stream>>>(part, kvcb, vcT);

    // ---- fused attention ----
    attn_k<<<dim3(LSEQ / 64, BB * HH), 256, 0, stream>>>(qb, kvcb, vcT, lngb);

    // ---- o-proj + fused LN(sb + short + lng) -> h1b ----
    gemm_ln_k<1, 32><<<dim3(1, 256), 256, 0, stream>>>(
        lngb, oT, o_b, 256, 256,
        ln1_g, ln1_b, nullptr, nullptr, nullptr, nullptr,
        sb, shortb16, h1b, nullptr, nullptr, nullptr);

    // FFN
    mfma_gemm_k<128, 128, 1, 1><<<dim3(8, 64, 1), 256, 0, stream>>>(
        h1b, f1T, f1_b, ffh, ML, 1024, 256, 256, 256, 1024,
        0, 0, 0, 0, 0, 0, 1, 0, 0, 0, 0, 1.f);

    // ---- f2 + fused LN(h1 + ff2) -> out (fp32) ----
    gemm_ln_k<2, 32><<<dim3(1, 256), 256, 0, stream>>>(
        ffh, f2T, f2_b, 1024, 1024,
        ln2_g, ln2_b, nullptr, nullptr, nullptr, nullptr,
        h1b, nullptr, nullptr, nullptr, nullptr, out);
}